// Round 1
// baseline (240.527 us; speedup 1.0000x reference)
//
#include <hip/hip_runtime.h>
#include <hip/hip_bf16.h>

#define T_TOK 16384
#define D_DIM 2048
#define E_EXP 64
#define TAU   2e-3f

typedef __bf16 bf16x8 __attribute__((ext_vector_type(8)));
typedef float  f32x16 __attribute__((ext_vector_type(16)));

// workspace layout (bytes)
#define WS_WHI  0                    // ushort[64*2048]  = 256KB  W hi bf16
#define WS_WLO  (256*1024)           // ushort[64*2048]  = 256KB  W lo bf16
#define WS_SUM  (512*1024)           // double[64] expert prob sums
#define WS_CNT  (512*1024 + 512)     // int flag count
#define WS_FLG  (512*1024 + 1024)    // int[T] flagged rows

__device__ __forceinline__ unsigned short bf16_rne(float x){
  unsigned int u = __float_as_uint(x);
  return (unsigned short)((u + 0x7FFFu + ((u >> 16) & 1u)) >> 16);
}

__device__ __forceinline__ void ins3(float& v1, int& i1, float& v2, int& i2,
                                     float& v3, int& i3, float v, int i){
  if (v > v1 || (v == v1 && i < i1)) { v3=v2; i3=i2; v2=v1; i2=i1; v1=v; i1=i; }
  else if (v > v2 || (v == v2 && i < i2)) { v3=v2; i3=i2; v2=v; i2=i; }
  else if (v > v3 || (v == v3 && i < i3)) { v3=v; i3=i; }
}

// Split W into hi/lo bf16 (internal precision scheme; any faithful rounding works)
__global__ void wsplit_kernel(const float* __restrict__ W,
                              unsigned short* __restrict__ whi,
                              unsigned short* __restrict__ wlo){
  int i = blockIdx.x * 256 + threadIdx.x;   // grid 512 -> 131072 elems
  float x = W[i];
  unsigned short h = bf16_rne(x);
  float hf = __uint_as_float(((unsigned int)h) << 16);
  whi[i] = h;
  wlo[i] = bf16_rne(x - hf);
}

// Main fused kernel: GEMM (split-bf16 MFMA) + noisy top-2 gating + prob accumulation
__launch_bounds__(256, 2)
__global__ void moe_main(const float* __restrict__ X, const float* __restrict__ NZ,
                         const unsigned short* __restrict__ WHI,
                         const unsigned short* __restrict__ WLO,
                         const float* __restrict__ NW, float* __restrict__ OUT,
                         double* __restrict__ ESUM, int* __restrict__ FCNT,
                         int* __restrict__ FLIST)
{
  __shared__ __align__(16) char smem[49152];
  unsigned short* xs_hi = (unsigned short*)(smem);          // [2][32][64]
  unsigned short* xs_lo = (unsigned short*)(smem + 8192);
  unsigned short* w_hi  = (unsigned short*)(smem + 16384);  // [2][64][64]
  unsigned short* w_lo  = (unsigned short*)(smem + 32768);

  const int tid  = threadIdx.x;
  const int lane = tid & 63;
  const int wv   = tid >> 6;   // 0..3
  const int kh   = wv >> 1;    // K half owned by this wave
  const int nt   = wv & 1;     // N tile (32 experts)
  const int r0   = blockIdx.x << 5;

  const int hx = tid >> 7;     // x-staging half
  const int tp = tid & 127;

  f32x16 acc;
  #pragma unroll
  for (int i = 0; i < 16; ++i) acc[i] = 0.0f;

  float4 xr[4];
  uint4  wrh[4], wrl[4];

  // prologue: prefetch iter 0
  #pragma unroll
  for (int i = 0; i < 4; ++i){
    int flat = i*128 + tp, row = flat >> 4, c4 = flat & 15;
    xr[i] = *reinterpret_cast<const float4*>(X + (size_t)(r0+row)*D_DIM + hx*1024 + c4*4);
    int f2 = i*256 + tid, r128 = f2 >> 3, c8 = f2 & 7;
    int hh = r128 >> 6, e = r128 & 63;
    size_t g = (size_t)e*D_DIM + hh*1024 + c8*8;
    wrh[i] = *reinterpret_cast<const uint4*>(WHI + g);
    wrl[i] = *reinterpret_cast<const uint4*>(WLO + g);
  }

  for (int it = 0; it < 16; ++it){
    // write staged regs to LDS (convert x to hi/lo bf16), XOR-swizzled rows
    #pragma unroll
    for (int i = 0; i < 4; ++i){
      int flat = i*128 + tp, row = flat >> 4, c4 = flat & 15;
      float a = xr[i].x, b = xr[i].y, c = xr[i].z, d = xr[i].w;
      unsigned short h0 = bf16_rne(a), h1 = bf16_rne(b), h2 = bf16_rne(c), h3 = bf16_rne(d);
      unsigned short l0 = bf16_rne(a - __uint_as_float(((unsigned)h0) << 16));
      unsigned short l1 = bf16_rne(b - __uint_as_float(((unsigned)h1) << 16));
      unsigned short l2 = bf16_rne(c - __uint_as_float(((unsigned)h2) << 16));
      unsigned short l3 = bf16_rne(d - __uint_as_float(((unsigned)h3) << 16));
      int sidx = (((hx*32 + row) << 6) + (c4 << 2)) ^ ((row & 7) << 3);
      *reinterpret_cast<ushort4*>(&xs_hi[sidx]) = make_ushort4(h0,h1,h2,h3);
      *reinterpret_cast<ushort4*>(&xs_lo[sidx]) = make_ushort4(l0,l1,l2,l3);

      int f2 = i*256 + tid, r128 = f2 >> 3, c8 = f2 & 7;
      int hh = r128 >> 6, e = r128 & 63;
      int widx = (((hh*64 + e) << 6) + (c8 << 3)) ^ ((e & 7) << 3);
      *reinterpret_cast<uint4*>(&w_hi[widx]) = wrh[i];
      *reinterpret_cast<uint4*>(&w_lo[widx]) = wrl[i];
    }
    __syncthreads();
    if (it < 15){
      #pragma unroll
      for (int i = 0; i < 4; ++i){
        int flat = i*128 + tp, row = flat >> 4, c4 = flat & 15;
        xr[i] = *reinterpret_cast<const float4*>(X + (size_t)(r0+row)*D_DIM + hx*1024 + (it+1)*64 + c4*4);
        int f2 = i*256 + tid, r128 = f2 >> 3, c8 = f2 & 7;
        int hh = r128 >> 6, e = r128 & 63;
        size_t g = (size_t)e*D_DIM + hh*1024 + (size_t)(it+1)*64 + c8*8;
        wrh[i] = *reinterpret_cast<const uint4*>(WHI + g);
        wrl[i] = *reinterpret_cast<const uint4*>(WLO + g);
      }
    }
    // compute: 4 k-slices x (hh, hl, lh). A and B use the SAME slot->k mapping,
    // so correctness is independent of the HW's internal k ordering.
    {
      const int m  = lane & 31;
      const int kg = lane >> 5;
      const int e  = nt*32 + m;
      #pragma unroll
      for (int ks = 0; ks < 4; ++ks){
        int aidx = (((kh*32 + m) << 6) + ks*16 + kg*8) ^ ((m & 7) << 3);
        int bidx = (((kh*64 + e) << 6) + ks*16 + kg*8) ^ ((e & 7) << 3);
        bf16x8 ah = *reinterpret_cast<const bf16x8*>(&xs_hi[aidx]);
        bf16x8 al = *reinterpret_cast<const bf16x8*>(&xs_lo[aidx]);
        bf16x8 bh = *reinterpret_cast<const bf16x8*>(&w_hi[bidx]);
        bf16x8 bl = *reinterpret_cast<const bf16x8*>(&w_lo[bidx]);
        acc = __builtin_amdgcn_mfma_f32_32x32x16_bf16(ah, bh, acc, 0, 0, 0);
        acc = __builtin_amdgcn_mfma_f32_32x32x16_bf16(ah, bl, acc, 0, 0, 0);
        acc = __builtin_amdgcn_mfma_f32_32x32x16_bf16(al, bh, acc, 0, 0, 0);
      }
    }
    __syncthreads();
  }

  // ---- epilogue: reduce K halves, then fused gating ----
  float* red  = (float*)(smem + 16384);   // [2][32][32]
  float* lgts = (float*)(smem + 24576);   // [32][64]
  float* prb  = (float*)(smem + 32768);   // [32][64]
  float* nzs  = (float*)(smem);           // [32][64] noise tile
  float* nws  = (float*)(smem + 8192);    // [64] noise_weight

  {
    const int m = lane & 31, kg = lane >> 5;
    if (kh == 1){
      #pragma unroll
      for (int r = 0; r < 16; ++r){
        int rr = (r & 3) + ((r >> 2) << 3) + (kg << 2);
        red[((nt << 5) | rr)*32 + m] = acc[r];
      }
    }
    __syncthreads();
    if (kh == 0){
      #pragma unroll
      for (int r = 0; r < 16; ++r){
        int rr = (r & 3) + ((r >> 2) << 3) + (kg << 2);
        lgts[rr*64 + (nt << 5) + m] = acc[r] + red[((nt << 5) | rr)*32 + m];
      }
    }
    __syncthreads();
  }
  // stage noise tile (coalesced) + noise_weight
  #pragma unroll
  for (int i = 0; i < 2; ++i){
    int flat = i*256 + tid, row = flat >> 4, c4 = flat & 15;
    *reinterpret_cast<float4*>(&nzs[row*64 + c4*4]) =
      *reinterpret_cast<const float4*>(NZ + (size_t)(r0+row)*E_EXP + c4*4);
  }
  if (tid < 64) nws[tid] = NW[tid];
  __syncthreads();

  // gating: 8 lanes per row, 8 experts per lane
  const int rrow = (wv << 3) + (lane >> 3);
  const int j    = lane & 7;
  const int trow = r0 + rrow;
  float cl[8];
  float v1 = -INFINITY, v2 = -INFINITY, v3 = -INFINITY;
  int   i1 = 1 << 29,   i2 = 1 << 29,   i3 = 1 << 29;
  #pragma unroll
  for (int mm = 0; mm < 8; ++mm){
    int e = j + (mm << 3);
    float lg = lgts[rrow*64 + e];
    cl[mm] = lg;
    float vn = fmaf(nzs[rrow*64 + e], nws[e], lg);   // NOISY_STD = 1
    ins3(v1,i1,v2,i2,v3,i3, vn, e);
  }
  #pragma unroll
  for (int d = 1; d < 8; d <<= 1){
    float ov1 = __shfl_xor(v1, d, 8), ov2 = __shfl_xor(v2, d, 8), ov3 = __shfl_xor(v3, d, 8);
    int   oi1 = __shfl_xor(i1, d, 8), oi2 = __shfl_xor(i2, d, 8), oi3 = __shfl_xor(i3, d, 8);
    ins3(v1,i1,v2,i2,v3,i3, ov1, oi1);
    ins3(v1,i1,v2,i2,v3,i3, ov2, oi2);
    ins3(v1,i1,v2,i2,v3,i3, ov3, oi3);
  }
  float e1 = expf(v2 - v1);
  float g0 = 1.0f / (1.0f + e1);
  float g1 = e1 * g0;

  // clean softmax for load-balance loss
  float mx = cl[0];
  #pragma unroll
  for (int mm = 1; mm < 8; ++mm) mx = fmaxf(mx, cl[mm]);
  #pragma unroll
  for (int d = 1; d < 8; d <<= 1) mx = fmaxf(mx, __shfl_xor(mx, d, 8));
  float sum = 0.0f, ex[8];
  #pragma unroll
  for (int mm = 0; mm < 8; ++mm){ ex[mm] = expf(cl[mm] - mx); sum += ex[mm]; }
  #pragma unroll
  for (int d = 1; d < 8; d <<= 1) sum += __shfl_xor(sum, d, 8);
  float inv = 1.0f / sum;
  #pragma unroll
  for (int mm = 0; mm < 8; ++mm) prb[rrow*64 + j + (mm << 3)] = ex[mm] * inv;

  if (j == 0){
    OUT[(size_t)T_TOK*E_EXP + (size_t)trow*2]     = (float)i1;
    OUT[(size_t)T_TOK*E_EXP + (size_t)trow*2 + 1] = (float)i2;
    if ((v1 - v2 < TAU) || (v2 - v3 < TAU)){     // near-tie: send to fp64 fixup
      int slot = atomicAdd(FCNT, 1);
      FLIST[slot] = trow;
    }
  }
  #pragma unroll
  for (int mm = 0; mm < 8; ++mm){
    int e = j + (mm << 3);
    lgts[rrow*64 + e] = (e == i1) ? g0 : ((e == i2) ? g1 : 0.0f);
  }
  __syncthreads();
  // coalesced gates write
  #pragma unroll
  for (int i = 0; i < 2; ++i){
    int flat = i*256 + tid, row = flat >> 4, c4 = flat & 15;
    *reinterpret_cast<float4*>(OUT + (size_t)(r0+row)*E_EXP + c4*4) =
      *reinterpret_cast<const float4*>(&lgts[row*64 + c4*4]);
  }
  // per-expert prob column sums -> one f64 atomic per expert per block
  if (tid < 64){
    float s0 = 0.0f;
    #pragma unroll 8
    for (int rr2 = 0; rr2 < 32; ++rr2) s0 += prb[rr2*64 + tid];
    atomicAdd(&ESUM[tid], (double)s0);
  }
}

// fp64-exact recompute of flagged (near-tie) rows; overwrites gates + ids
__global__ void moe_fixup(const float* __restrict__ X, const float* __restrict__ NZ,
                          const float* __restrict__ WG, const float* __restrict__ NW,
                          float* __restrict__ OUT, const int* __restrict__ FCNT,
                          const int* __restrict__ FLIST)
{
  __shared__ double part[256];
  __shared__ double lz[64];
  __shared__ int   si1, si2;
  __shared__ float sg0, sg1;
  const int n = *FCNT;
  const int e = threadIdx.x & 63;
  const int p = threadIdx.x >> 6;
  for (int idx = blockIdx.x; idx < n; idx += gridDim.x){
    const int t = FLIST[idx];
    const float* xr = X  + (size_t)t * D_DIM;
    const float* wr = WG + (size_t)e * D_DIM;
    double s = 0.0;
    for (int d = p*512; d < (p+1)*512; ++d) s += (double)xr[d] * (double)wr[d];
    part[threadIdx.x] = s;
    __syncthreads();
    if (threadIdx.x < 64){
      double l = part[e] + part[e+64] + part[e+128] + part[e+192];
      lz[e] = l + (double)NZ[(size_t)t*E_EXP + e] * (double)NW[e];
    }
    __syncthreads();
    if (threadIdx.x == 0){
      double b1 = -1e300, b2 = -1e300; int j1 = 0, j2 = 0;
      for (int q = 0; q < 64; ++q){
        double v = lz[q];
        if (v > b1){ b2 = b1; j2 = j1; b1 = v; j1 = q; }
        else if (v > b2){ b2 = v; j2 = q; }
      }
      double ee = exp(b2 - b1);
      sg0 = (float)(1.0 / (1.0 + ee));
      sg1 = (float)(ee / (1.0 + ee));
      si1 = j1; si2 = j2;
      OUT[(size_t)T_TOK*E_EXP + (size_t)t*2]     = (float)j1;
      OUT[(size_t)T_TOK*E_EXP + (size_t)t*2 + 1] = (float)j2;
    }
    __syncthreads();
    if (threadIdx.x < 64)
      OUT[(size_t)t*E_EXP + e] = (e == si1) ? sg0 : ((e == si2) ? sg1 : 0.0f);
    __syncthreads();
  }
}

__global__ void moe_loss(const double* __restrict__ ESUM, float* __restrict__ OUT){
  const int e = threadIdx.x;   // 64 threads
  double d = ESUM[e] * (1.0 / T_TOK) - (1.0 / 64.0);
  double sq = d * d;
  #pragma unroll
  for (int off = 1; off < 64; off <<= 1) sq += __shfl_xor(sq, off, 64);
  if (e == 0) OUT[(size_t)T_TOK*E_EXP + T_TOK*2] = (float)(sq * (0.01 / 64.0));
}

extern "C" void kernel_launch(void* const* d_in, const int* in_sizes, int n_in,
                              void* d_out, int out_size, void* d_ws, size_t ws_size,
                              hipStream_t stream)
{
  const float* X  = (const float*)d_in[0];
  const float* NZ = (const float*)d_in[1];
  const float* WG = (const float*)d_in[2];
  const float* NW = (const float*)d_in[3];
  float* OUT = (float*)d_out;
  char*  ws  = (char*)d_ws;
  unsigned short* WHI = (unsigned short*)(ws + WS_WHI);
  unsigned short* WLO = (unsigned short*)(ws + WS_WLO);
  double* ESUM = (double*)(ws + WS_SUM);
  int* FCNT  = (int*)(ws + WS_CNT);
  int* FLIST = (int*)(ws + WS_FLG);

  hipMemsetAsync(ws + WS_SUM, 0, 1024, stream);  // expert sums + flag count
  wsplit_kernel<<<dim3(512), dim3(256), 0, stream>>>(WG, WHI, WLO);
  moe_main<<<dim3(T_TOK/32), dim3(256), 0, stream>>>(X, NZ, WHI, WLO, NW, OUT, ESUM, FCNT, FLIST);
  moe_fixup<<<dim3(256), dim3(256), 0, stream>>>(X, NZ, WG, NW, OUT, FCNT, FLIST);
  moe_loss<<<dim3(1), dim3(64), 0, stream>>>(ESUM, OUT);
}

// Round 2
// 211.782 us; speedup vs baseline: 1.1357x; 1.1357x over previous
//
#include <hip/hip_runtime.h>
#include <hip/hip_bf16.h>

#define T_TOK 16384
#define D_DIM 2048
#define E_EXP 64
#define TAU   2e-3f

typedef __bf16 bf16x8 __attribute__((ext_vector_type(8)));
typedef float  f32x16 __attribute__((ext_vector_type(16)));

// workspace layout (bytes)
#define WS_SUM  (512*1024)           // double[64] expert prob sums
#define WS_CNT  (512*1024 + 512)     // int flag count
#define WS_FLG  (512*1024 + 1024)    // int[T] flagged rows

__device__ __forceinline__ void split8(float4 a, float4 b, bf16x8& h, bf16x8& l){
  float f[8] = {a.x, a.y, a.z, a.w, b.x, b.y, b.z, b.w};
  #pragma unroll
  for (int i = 0; i < 8; ++i){
    __bf16 hi = (__bf16)f[i];          // RNE; compiler packs pairs via v_cvt_pk_bf16_f32
    h[i] = hi;
    l[i] = (__bf16)(f[i] - (float)hi); // residual is exact in f32 (Sterbenz)
  }
}

__device__ __forceinline__ void ins3(float& v1, int& i1, float& v2, int& i2,
                                     float& v3, int& i3, float v, int i){
  if (v > v1 || (v == v1 && i < i1)) { v3=v2; i3=i2; v2=v1; i2=i1; v1=v; i1=i; }
  else if (v > v2 || (v == v2 && i < i2)) { v3=v2; i3=i2; v2=v; i2=i; }
  else if (v > v3 || (v == v3 && i < i3)) { v3=v; i3=i; }
}

// Fused: split-bf16 MFMA GEMM (no LDS in K-loop, waves fully independent)
// + noisy top-2 gating + clean-softmax accumulation.
__launch_bounds__(512, 4)
__global__ void moe_main(const float* __restrict__ X, const float* __restrict__ NZ,
                         const float* __restrict__ WG, const float* __restrict__ NW,
                         float* __restrict__ OUT, double* __restrict__ ESUM,
                         int* __restrict__ FCNT, int* __restrict__ FLIST)
{
  __shared__ float lgts[32][64];
  __shared__ float nzs [32][64];
  __shared__ float prb [32][64];
  __shared__ float nws [64];

  const int tid  = threadIdx.x;
  const int lane = tid & 63;
  const int wv   = tid >> 6;   // 0..7
  const int kh   = wv >> 1;    // K quarter 0..3
  const int nt   = wv & 1;     // expert half
  const int r0   = blockIdx.x << 5;
  const int m    = lane & 31;
  const int kg   = lane >> 5;
  const int ex   = nt*32 + m;

  const float* xb = X  + (size_t)(r0 + m)*D_DIM + kh*512 + kg*8;
  const float* wb = WG + (size_t)ex      *D_DIM + kh*512 + kg*8;

  f32x16 acc;
  #pragma unroll
  for (int i = 0; i < 16; ++i) acc[i] = 0.0f;

  // K quarter = 512 -> 32 k-steps of 16. A and B use the SAME slot->k mapping,
  // so correctness is independent of the HW's internal k ordering.
  #pragma unroll 2
  for (int s = 0; s < 32; ++s){
    float4 xa = *reinterpret_cast<const float4*>(xb + s*16);
    float4 xc = *reinterpret_cast<const float4*>(xb + s*16 + 4);
    float4 wa = *reinterpret_cast<const float4*>(wb + s*16);
    float4 wc = *reinterpret_cast<const float4*>(wb + s*16 + 4);
    bf16x8 ah, al, bh, bl;
    split8(xa, xc, ah, al);
    split8(wa, wc, bh, bl);
    acc = __builtin_amdgcn_mfma_f32_32x32x16_bf16(ah, bh, acc, 0, 0, 0);
    acc = __builtin_amdgcn_mfma_f32_32x32x16_bf16(ah, bl, acc, 0, 0, 0);
    acc = __builtin_amdgcn_mfma_f32_32x32x16_bf16(al, bh, acc, 0, 0, 0);
  }

  // deterministic K-quarter reduction (barrier chain; disjoint cells per phase)
  #pragma unroll
  for (int p = 0; p < 4; ++p){
    if (kh == p){
      #pragma unroll
      for (int r = 0; r < 16; ++r){
        int rr = (r & 3) + ((r >> 2) << 3) + (kg << 2);  // verified 32x32 C/D layout
        if (p == 0) lgts[rr][ex] = acc[r];
        else        lgts[rr][ex] += acc[r];
      }
    }
    __syncthreads();
  }

  // stage noise tile + noise_weight
  {
    int row = tid >> 4, c4 = tid & 15;
    *reinterpret_cast<float4*>(&nzs[row][c4*4]) =
      *reinterpret_cast<const float4*>(NZ + (size_t)(r0 + row)*E_EXP + c4*4);
  }
  if (tid < 64) nws[tid] = NW[tid];
  __syncthreads();

  // gating: first 4 waves, 8 lanes per row, 8 experts per lane
  if (wv < 4){
    const int rrow = (wv << 3) + (lane >> 3);
    const int j    = lane & 7;
    const int trow = r0 + rrow;
    float cl[8];
    float v1 = -INFINITY, v2 = -INFINITY, v3 = -INFINITY;
    int   i1 = 1 << 29,   i2 = 1 << 29,   i3 = 1 << 29;
    #pragma unroll
    for (int mm = 0; mm < 8; ++mm){
      int q = j + (mm << 3);
      float lg = lgts[rrow][q];
      cl[mm] = lg;
      float vn = fmaf(nzs[rrow][q], nws[q], lg);   // NOISY_STD = 1
      ins3(v1,i1,v2,i2,v3,i3, vn, q);
    }
    #pragma unroll
    for (int d = 1; d < 8; d <<= 1){
      float ov1 = __shfl_xor(v1, d, 8), ov2 = __shfl_xor(v2, d, 8), ov3 = __shfl_xor(v3, d, 8);
      int   oi1 = __shfl_xor(i1, d, 8), oi2 = __shfl_xor(i2, d, 8), oi3 = __shfl_xor(i3, d, 8);
      ins3(v1,i1,v2,i2,v3,i3, ov1, oi1);
      ins3(v1,i1,v2,i2,v3,i3, ov2, oi2);
      ins3(v1,i1,v2,i2,v3,i3, ov3, oi3);
    }
    float e1 = expf(v2 - v1);
    float g0 = 1.0f / (1.0f + e1);
    float g1 = e1 * g0;

    // clean softmax for load-balance loss
    float mx = cl[0];
    #pragma unroll
    for (int mm = 1; mm < 8; ++mm) mx = fmaxf(mx, cl[mm]);
    #pragma unroll
    for (int d = 1; d < 8; d <<= 1) mx = fmaxf(mx, __shfl_xor(mx, d, 8));
    float sum = 0.0f, exv[8];
    #pragma unroll
    for (int mm = 0; mm < 8; ++mm){ exv[mm] = expf(cl[mm] - mx); sum += exv[mm]; }
    #pragma unroll
    for (int d = 1; d < 8; d <<= 1) sum += __shfl_xor(sum, d, 8);
    float inv = 1.0f / sum;
    #pragma unroll
    for (int mm = 0; mm < 8; ++mm) prb[rrow][j + (mm << 3)] = exv[mm] * inv;

    if (j == 0){
      OUT[(size_t)T_TOK*E_EXP + (size_t)trow*2]     = (float)i1;
      OUT[(size_t)T_TOK*E_EXP + (size_t)trow*2 + 1] = (float)i2;
      if ((v1 - v2 < TAU) || (v2 - v3 < TAU)){   // near-tie -> fp64 fixup
        int slot = atomicAdd(FCNT, 1);
        FLIST[slot] = trow;
      }
    }
    #pragma unroll
    for (int mm = 0; mm < 8; ++mm){
      int q = j + (mm << 3);
      lgts[rrow][q] = (q == i1) ? g0 : ((q == i2) ? g1 : 0.0f);
    }
  }
  __syncthreads();

  // coalesced gates write
  {
    int row = tid >> 4, c4 = tid & 15;
    *reinterpret_cast<float4*>(OUT + (size_t)(r0 + row)*E_EXP + c4*4) =
      *reinterpret_cast<const float4*>(&lgts[row][c4*4]);
  }
  // per-expert prob column sums -> one f64 atomic per expert per block
  if (tid < 64){
    float s0 = 0.0f;
    #pragma unroll 8
    for (int rr2 = 0; rr2 < 32; ++rr2) s0 += prb[rr2][tid];
    atomicAdd(&ESUM[tid], (double)s0);
  }
}

// fp64-exact recompute of flagged (near-tie) rows; overwrites gates + ids
__global__ void moe_fixup(const float* __restrict__ X, const float* __restrict__ NZ,
                          const float* __restrict__ WG, const float* __restrict__ NW,
                          float* __restrict__ OUT, const int* __restrict__ FCNT,
                          const int* __restrict__ FLIST)
{
  __shared__ double part[256];
  __shared__ double lz[64];
  __shared__ int   si1, si2;
  __shared__ float sg0, sg1;
  const int n = *FCNT;
  const int e = threadIdx.x & 63;
  const int p = threadIdx.x >> 6;
  for (int idx = blockIdx.x; idx < n; idx += gridDim.x){
    const int t = FLIST[idx];
    const float* xr = X  + (size_t)t * D_DIM;
    const float* wr = WG + (size_t)e * D_DIM;
    double s = 0.0;
    for (int d = p*512; d < (p+1)*512; ++d) s += (double)xr[d] * (double)wr[d];
    part[threadIdx.x] = s;
    __syncthreads();
    if (threadIdx.x < 64){
      double l = part[e] + part[e+64] + part[e+128] + part[e+192];
      lz[e] = l + (double)NZ[(size_t)t*E_EXP + e] * (double)NW[e];
    }
    __syncthreads();
    if (threadIdx.x == 0){
      double b1 = -1e300, b2 = -1e300; int j1 = 0, j2 = 0;
      for (int q = 0; q < 64; ++q){
        double v = lz[q];
        if (v > b1){ b2 = b1; j2 = j1; b1 = v; j1 = q; }
        else if (v > b2){ b2 = v; j2 = q; }
      }
      double ee = exp(b2 - b1);
      sg0 = (float)(1.0 / (1.0 + ee));
      sg1 = (float)(ee / (1.0 + ee));
      si1 = j1; si2 = j2;
      OUT[(size_t)T_TOK*E_EXP + (size_t)t*2]     = (float)j1;
      OUT[(size_t)T_TOK*E_EXP + (size_t)t*2 + 1] = (float)j2;
    }
    __syncthreads();
    if (threadIdx.x < 64)
      OUT[(size_t)t*E_EXP + e] = (e == si1) ? sg0 : ((e == si2) ? sg1 : 0.0f);
    __syncthreads();
  }
}

__global__ void moe_loss(const double* __restrict__ ESUM, float* __restrict__ OUT){
  const int e = threadIdx.x;   // 64 threads
  double d = ESUM[e] * (1.0 / T_TOK) - (1.0 / 64.0);
  double sq = d * d;
  #pragma unroll
  for (int off = 1; off < 64; off <<= 1) sq += __shfl_xor(sq, off, 64);
  if (e == 0) OUT[(size_t)T_TOK*E_EXP + T_TOK*2] = (float)(sq * (0.01 / 64.0));
}

extern "C" void kernel_launch(void* const* d_in, const int* in_sizes, int n_in,
                              void* d_out, int out_size, void* d_ws, size_t ws_size,
                              hipStream_t stream)
{
  const float* X  = (const float*)d_in[0];
  const float* NZ = (const float*)d_in[1];
  const float* WG = (const float*)d_in[2];
  const float* NW = (const float*)d_in[3];
  float* OUT = (float*)d_out;
  char*  ws  = (char*)d_ws;
  double* ESUM = (double*)(ws + WS_SUM);
  int* FCNT  = (int*)(ws + WS_CNT);
  int* FLIST = (int*)(ws + WS_FLG);

  hipMemsetAsync(ws + WS_SUM, 0, 1024, stream);  // expert sums + flag count
  moe_main<<<dim3(T_TOK/32), dim3(512), 0, stream>>>(X, NZ, WG, NW, OUT, ESUM, FCNT, FLIST);
  moe_fixup<<<dim3(256), dim3(256), 0, stream>>>(X, NZ, WG, NW, OUT, FCNT, FLIST);
  moe_loss<<<dim3(1), dim3(64), 0, stream>>>(ESUM, OUT);
}

// Round 3
// 118.848 us; speedup vs baseline: 2.0238x; 1.7820x over previous
//
#include <hip/hip_runtime.h>
#include <hip/hip_bf16.h>

#define T_TOK 16384
#define D_DIM 2048
#define E_EXP 64
#define TAU   2e-3f

typedef __bf16 bf16x8 __attribute__((ext_vector_type(8)));
typedef float  f32x16 __attribute__((ext_vector_type(16)));

// workspace layout (bytes)
#define WS_WHI  0                    // ushort[64*2048] = 256KB  W hi bf16
#define WS_WLO  (256*1024)           // ushort[64*2048] = 256KB  W lo bf16
#define WS_SUM  (512*1024)           // double[64] expert prob sums
#define WS_CNT  (512*1024 + 512)     // int flag count
#define WS_FLG  (512*1024 + 1024)    // int[T] flagged rows

__device__ __forceinline__ unsigned short bf16_rne(float x){
  unsigned int u = __float_as_uint(x);
  return (unsigned short)((u + 0x7FFFu + ((u >> 16) & 1u)) >> 16);
}

__device__ __forceinline__ void ins3(float& v1, int& i1, float& v2, int& i2,
                                     float& v3, int& i3, float v, int i){
  if (v > v1 || (v == v1 && i < i1)) { v3=v2; i3=i2; v2=v1; i2=i1; v1=v; i1=i; }
  else if (v > v2 || (v == v2 && i < i2)) { v3=v2; i3=i2; v2=v; i2=i; }
  else if (v > v3 || (v == v3 && i < i3)) { v3=v; i3=i; }
}

__global__ void wsplit_kernel(const float* __restrict__ W,
                              unsigned short* __restrict__ whi,
                              unsigned short* __restrict__ wlo){
  int i = blockIdx.x * 256 + threadIdx.x;   // grid 512 -> 131072 elems
  float x = W[i];
  unsigned short h = bf16_rne(x);
  whi[i] = h;
  wlo[i] = bf16_rne(x - __uint_as_float(((unsigned int)h) << 16));
}

// Main fused kernel: staged split-bf16 MFMA GEMM + noisy top-2 gating.
// Tile: 32 rows x 64 experts, BK=64 f32, double-buffered LDS (2x24KB).
// LDS layout per buffer: XHI[32][64]bf16 @0, XLO @4K, WHI[64][64] @8K, WLO @16K.
// 16B-granule XOR swizzle: logical granule g of row r lives at g^(r&7)
// -> conflict-free ds_read_b128 and ds_write_b128 (verified: 8 lanes/granule).
__launch_bounds__(256, 2)
__global__ void moe_main(const float* __restrict__ X, const float* __restrict__ NZ,
                         const unsigned short* __restrict__ WHI,
                         const unsigned short* __restrict__ WLO,
                         const float* __restrict__ NW, float* __restrict__ OUT,
                         double* __restrict__ ESUM, int* __restrict__ FCNT,
                         int* __restrict__ FLIST)
{
  __shared__ __align__(16) char smem[49152];

  const int tid  = threadIdx.x;
  const int lane = tid & 63;
  const int wv   = tid >> 6;   // 0..3
  const int nt   = wv & 1;     // expert half
  const int kh   = wv >> 1;    // k half of the chunk
  const int r0   = blockIdx.x << 5;
  const int m    = lane & 31;
  const int kg   = lane >> 5;
  const int ex   = nt*32 + m;

  // staging: X  -> thread covers row sr, granule sc (8 f32 = 32B in, 16B hi + 16B lo out)
  const int sr = tid >> 3, sc = tid & 7;
  // staging: W  -> thread covers expert we, 32B part wp (16 bf16 per operand)
  const int we = tid >> 2, wp = tid & 3;

  const float*          xg  = X   + (size_t)(r0 + sr)*D_DIM + sc*8;
  const unsigned short* whg = WHI + (size_t)we*D_DIM + wp*16;
  const unsigned short* wlg = WLO + (size_t)we*D_DIM + wp*16;

  const int xw_hi = sr*128 + ((sc ^ (sr & 7)) << 4);            // byte off in buffer
  const int ww_g0 = ((wp*2)     ^ (we & 7)) << 4;
  const int ww_g1 = ((wp*2 + 1) ^ (we & 7)) << 4;
  const int ww_row = we*128;

  f32x16 acc;
  #pragma unroll
  for (int i = 0; i < 16; ++i) acc[i] = 0.0f;

  float4 xa, xb; uint4 wh0, wh1, wl0, wl1;

  // ---- staging helpers (macros keep everything in registers, fully unrolled) ----
  #define LOAD_CHUNK(c) do {                                                   \
    xa  = *reinterpret_cast<const float4*>(xg  + (c)*64);                      \
    xb  = *reinterpret_cast<const float4*>(xg  + (c)*64 + 4);                  \
    wh0 = *reinterpret_cast<const uint4*>(whg + (c)*64);                       \
    wh1 = *reinterpret_cast<const uint4*>(whg + (c)*64 + 8);                   \
    wl0 = *reinterpret_cast<const uint4*>(wlg + (c)*64);                       \
    wl1 = *reinterpret_cast<const uint4*>(wlg + (c)*64 + 8);                   \
  } while(0)

  #define WRITE_CHUNK(bufbase) do {                                            \
    char* Bp = smem + (bufbase);                                               \
    float f0=xa.x, f1=xa.y, f2=xa.z, f3=xa.w, f4=xb.x, f5=xb.y, f6=xb.z, f7=xb.w; \
    unsigned short h0=bf16_rne(f0),h1=bf16_rne(f1),h2=bf16_rne(f2),h3=bf16_rne(f3); \
    unsigned short h4=bf16_rne(f4),h5=bf16_rne(f5),h6=bf16_rne(f6),h7=bf16_rne(f7); \
    uint4 hv, lv;                                                              \
    hv.x = h0 | ((unsigned)h1<<16); hv.y = h2 | ((unsigned)h3<<16);            \
    hv.z = h4 | ((unsigned)h5<<16); hv.w = h6 | ((unsigned)h7<<16);            \
    lv.x = bf16_rne(f0-__uint_as_float((unsigned)h0<<16)) |                    \
           ((unsigned)bf16_rne(f1-__uint_as_float((unsigned)h1<<16))<<16);     \
    lv.y = bf16_rne(f2-__uint_as_float((unsigned)h2<<16)) |                    \
           ((unsigned)bf16_rne(f3-__uint_as_float((unsigned)h3<<16))<<16);     \
    lv.z = bf16_rne(f4-__uint_as_float((unsigned)h4<<16)) |                    \
           ((unsigned)bf16_rne(f5-__uint_as_float((unsigned)h5<<16))<<16);     \
    lv.w = bf16_rne(f6-__uint_as_float((unsigned)h6<<16)) |                    \
           ((unsigned)bf16_rne(f7-__uint_as_float((unsigned)h7<<16))<<16);     \
    *reinterpret_cast<uint4*>(Bp + xw_hi)          = hv;                       \
    *reinterpret_cast<uint4*>(Bp + 4096 + xw_hi)   = lv;                       \
    *reinterpret_cast<uint4*>(Bp + 8192  + ww_row + ww_g0) = wh0;              \
    *reinterpret_cast<uint4*>(Bp + 8192  + ww_row + ww_g1) = wh1;              \
    *reinterpret_cast<uint4*>(Bp + 16384 + ww_row + ww_g0) = wl0;              \
    *reinterpret_cast<uint4*>(Bp + 16384 + ww_row + ww_g1) = wl1;              \
  } while(0)

  // prologue
  LOAD_CHUNK(0);
  WRITE_CHUNK(0);
  __syncthreads();

  #pragma unroll 2
  for (int c = 0; c < 32; ++c){
    const int bufbase = (c & 1) * 24576;
    if (c < 31) LOAD_CHUNK(c + 1);
    {
      const char* Bp = smem + bufbase;
      #pragma unroll
      for (int ks2 = 0; ks2 < 2; ++ks2){
        const int ks = kh*2 + ks2;
        const int g0 = ks*2 + kg;
        bf16x8 ah = *reinterpret_cast<const bf16x8*>(Bp +         m*128  + ((g0 ^ (m  & 7)) << 4));
        bf16x8 al = *reinterpret_cast<const bf16x8*>(Bp + 4096  + m*128  + ((g0 ^ (m  & 7)) << 4));
        bf16x8 bh = *reinterpret_cast<const bf16x8*>(Bp + 8192  + ex*128 + ((g0 ^ (ex & 7)) << 4));
        bf16x8 bl = *reinterpret_cast<const bf16x8*>(Bp + 16384 + ex*128 + ((g0 ^ (ex & 7)) << 4));
        acc = __builtin_amdgcn_mfma_f32_32x32x16_bf16(ah, bh, acc, 0, 0, 0);
        acc = __builtin_amdgcn_mfma_f32_32x32x16_bf16(ah, bl, acc, 0, 0, 0);
        acc = __builtin_amdgcn_mfma_f32_32x32x16_bf16(al, bh, acc, 0, 0, 0);
      }
    }
    if (c < 31) WRITE_CHUNK((c & 1) ? 0 : 24576);
    __syncthreads();
  }
  #undef LOAD_CHUNK
  #undef WRITE_CHUNK

  // ---- epilogue ----
  float* lgts = (float*)(smem);            // [32][64]
  float* nzs  = (float*)(smem + 8192);     // [32][64]
  float* prb  = (float*)(smem + 16384);    // [32][64]
  float* nws  = (float*)(smem + 24576);    // [64]

  // k-half reduction, deterministic 2-phase
  if (kh == 0){
    #pragma unroll
    for (int r = 0; r < 16; ++r){
      int rr = (r & 3) + ((r >> 2) << 3) + (kg << 2);   // verified 32x32 C/D layout
      lgts[rr*64 + ex] = acc[r];
    }
  }
  __syncthreads();
  if (kh == 1){
    #pragma unroll
    for (int r = 0; r < 16; ++r){
      int rr = (r & 3) + ((r >> 2) << 3) + (kg << 2);
      lgts[rr*64 + ex] += acc[r];
    }
  }
  // stage noise + noise_weight
  {
    *reinterpret_cast<float4*>(&nzs[sr*64 + sc*8]) =
      *reinterpret_cast<const float4*>(NZ + (size_t)(r0 + sr)*E_EXP + sc*8);
    *reinterpret_cast<float4*>(&nzs[sr*64 + sc*8 + 4]) =
      *reinterpret_cast<const float4*>(NZ + (size_t)(r0 + sr)*E_EXP + sc*8 + 4);
  }
  if (tid < 64) nws[tid] = NW[tid];
  __syncthreads();

  // gating: 8 lanes per row, 8 experts per lane (all 4 waves -> 32 rows)
  {
    const int rrow = (wv << 3) + (lane >> 3);
    const int j    = lane & 7;
    const int trow = r0 + rrow;
    float cl[8];
    float v1 = -INFINITY, v2 = -INFINITY, v3 = -INFINITY;
    int   i1 = 1 << 29,   i2 = 1 << 29,   i3 = 1 << 29;
    #pragma unroll
    for (int mm = 0; mm < 8; ++mm){
      int q = j + (mm << 3);
      float lg = lgts[rrow*64 + q];
      cl[mm] = lg;
      float vn = fmaf(nzs[rrow*64 + q], nws[q], lg);   // NOISY_STD = 1
      ins3(v1,i1,v2,i2,v3,i3, vn, q);
    }
    #pragma unroll
    for (int d = 1; d < 8; d <<= 1){
      float ov1 = __shfl_xor(v1, d, 8), ov2 = __shfl_xor(v2, d, 8), ov3 = __shfl_xor(v3, d, 8);
      int   oi1 = __shfl_xor(i1, d, 8), oi2 = __shfl_xor(i2, d, 8), oi3 = __shfl_xor(i3, d, 8);
      ins3(v1,i1,v2,i2,v3,i3, ov1, oi1);
      ins3(v1,i1,v2,i2,v3,i3, ov2, oi2);
      ins3(v1,i1,v2,i2,v3,i3, ov3, oi3);
    }
    float e1 = expf(v2 - v1);
    float g0 = 1.0f / (1.0f + e1);
    float g1 = e1 * g0;

    float mx = cl[0];
    #pragma unroll
    for (int mm = 1; mm < 8; ++mm) mx = fmaxf(mx, cl[mm]);
    #pragma unroll
    for (int d = 1; d < 8; d <<= 1) mx = fmaxf(mx, __shfl_xor(mx, d, 8));
    float sum = 0.0f, exv[8];
    #pragma unroll
    for (int mm = 0; mm < 8; ++mm){ exv[mm] = expf(cl[mm] - mx); sum += exv[mm]; }
    #pragma unroll
    for (int d = 1; d < 8; d <<= 1) sum += __shfl_xor(sum, d, 8);
    float inv = 1.0f / sum;
    #pragma unroll
    for (int mm = 0; mm < 8; ++mm) prb[rrow*64 + j + (mm << 3)] = exv[mm] * inv;

    if (j == 0){
      OUT[(size_t)T_TOK*E_EXP + (size_t)trow*2]     = (float)i1;
      OUT[(size_t)T_TOK*E_EXP + (size_t)trow*2 + 1] = (float)i2;
      if ((v1 - v2 < TAU) || (v2 - v3 < TAU)){   // near-tie -> fp64 fixup
        int slot = atomicAdd(FCNT, 1);
        FLIST[slot] = trow;
      }
    }
    #pragma unroll
    for (int mm = 0; mm < 8; ++mm){
      int q = j + (mm << 3);
      lgts[rrow*64 + q] = (q == i1) ? g0 : ((q == i2) ? g1 : 0.0f);
    }
  }
  __syncthreads();

  // coalesced gates write
  {
    *reinterpret_cast<float4*>(OUT + (size_t)(r0 + sr)*E_EXP + sc*8) =
      *reinterpret_cast<const float4*>(&lgts[sr*64 + sc*8]);
    *reinterpret_cast<float4*>(OUT + (size_t)(r0 + sr)*E_EXP + sc*8 + 4) =
      *reinterpret_cast<const float4*>(&lgts[sr*64 + sc*8 + 4]);
  }
  if (tid < 64){
    float s0 = 0.0f;
    #pragma unroll 8
    for (int rr2 = 0; rr2 < 32; ++rr2) s0 += prb[rr2*64 + tid];
    atomicAdd(&ESUM[tid], (double)s0);
  }
}

// fp64-exact recompute of flagged (near-tie) rows; coalesced, one block/row.
__launch_bounds__(256)
__global__ void moe_fixup(const float* __restrict__ X, const float* __restrict__ NZ,
                          const float* __restrict__ WG, const float* __restrict__ NW,
                          float* __restrict__ OUT, const int* __restrict__ FCNT,
                          const int* __restrict__ FLIST)
{
  __shared__ __align__(16) float xl[2048];
  __shared__ double lz[64];
  __shared__ int   si1, si2;
  __shared__ float sg0, sg1;
  const int n    = *FCNT;
  const int lane = threadIdx.x & 63;
  const int wv   = threadIdx.x >> 6;
  for (int idx = blockIdx.x; idx < n; idx += gridDim.x){
    const int t = FLIST[idx];
    {
      int off = threadIdx.x * 8;
      *reinterpret_cast<float4*>(xl + off) =
        *reinterpret_cast<const float4*>(X + (size_t)t*D_DIM + off);
      *reinterpret_cast<float4*>(xl + off + 4) =
        *reinterpret_cast<const float4*>(X + (size_t)t*D_DIM + off + 4);
    }
    __syncthreads();
    for (int s = 0; s < 16; ++s){
      const int e = wv*16 + s;
      const float* wr = WG + (size_t)e*D_DIM;
      double acc = 0.0;
      #pragma unroll
      for (int it = 0; it < 8; ++it){
        float4 w4 = *reinterpret_cast<const float4*>(wr + it*256 + lane*4);
        float4 x4 = *reinterpret_cast<const float4*>(xl + it*256 + lane*4);
        acc += (double)x4.x * (double)w4.x;
        acc += (double)x4.y * (double)w4.y;
        acc += (double)x4.z * (double)w4.z;
        acc += (double)x4.w * (double)w4.w;
      }
      #pragma unroll
      for (int off = 1; off < 64; off <<= 1) acc += __shfl_xor(acc, off, 64);
      if (lane == 0)
        lz[e] = acc + (double)NZ[(size_t)t*E_EXP + e] * (double)NW[e];
    }
    __syncthreads();
    if (threadIdx.x == 0){
      double b1 = -1e300, b2 = -1e300; int j1 = 0, j2 = 0;
      for (int q = 0; q < 64; ++q){
        double v = lz[q];
        if (v > b1){ b2 = b1; j2 = j1; b1 = v; j1 = q; }
        else if (v > b2){ b2 = v; j2 = q; }
      }
      double ee = exp(b2 - b1);
      sg0 = (float)(1.0 / (1.0 + ee));
      sg1 = (float)(ee / (1.0 + ee));
      si1 = j1; si2 = j2;
      OUT[(size_t)T_TOK*E_EXP + (size_t)t*2]     = (float)j1;
      OUT[(size_t)T_TOK*E_EXP + (size_t)t*2 + 1] = (float)j2;
    }
    __syncthreads();
    if (threadIdx.x < 64)
      OUT[(size_t)t*E_EXP + threadIdx.x] = (threadIdx.x == si1) ? sg0 :
                                           ((threadIdx.x == si2) ? sg1 : 0.0f);
    __syncthreads();
  }
}

__global__ void moe_loss(const double* __restrict__ ESUM, float* __restrict__ OUT){
  const int e = threadIdx.x;   // 64 threads
  double d = ESUM[e] * (1.0 / T_TOK) - (1.0 / 64.0);
  double sq = d * d;
  #pragma unroll
  for (int off = 1; off < 64; off <<= 1) sq += __shfl_xor(sq, off, 64);
  if (e == 0) OUT[(size_t)T_TOK*E_EXP + T_TOK*2] = (float)(sq * (0.01 / 64.0));
}

extern "C" void kernel_launch(void* const* d_in, const int* in_sizes, int n_in,
                              void* d_out, int out_size, void* d_ws, size_t ws_size,
                              hipStream_t stream)
{
  const float* X  = (const float*)d_in[0];
  const float* NZ = (const float*)d_in[1];
  const float* WG = (const float*)d_in[2];
  const float* NW = (const float*)d_in[3];
  float* OUT = (float*)d_out;
  char*  ws  = (char*)d_ws;
  unsigned short* WHI = (unsigned short*)(ws + WS_WHI);
  unsigned short* WLO = (unsigned short*)(ws + WS_WLO);
  double* ESUM = (double*)(ws + WS_SUM);
  int* FCNT  = (int*)(ws + WS_CNT);
  int* FLIST = (int*)(ws + WS_FLG);

  hipMemsetAsync(ws + WS_SUM, 0, 1024, stream);  // expert sums + flag count
  wsplit_kernel<<<dim3(512), dim3(256), 0, stream>>>(WG, WHI, WLO);
  moe_main<<<dim3(T_TOK/32), dim3(256), 0, stream>>>(X, NZ, WHI, WLO, NW, OUT, ESUM, FCNT, FLIST);
  moe_fixup<<<dim3(512), dim3(256), 0, stream>>>(X, NZ, WG, NW, OUT, FCNT, FLIST);
  moe_loss<<<dim3(1), dim3(64), 0, stream>>>(ESUM, OUT);
}

// Round 4
// 114.380 us; speedup vs baseline: 2.1029x; 1.0391x over previous
//
#include <hip/hip_runtime.h>
#include <hip/hip_bf16.h>

#define T_TOK 16384
#define D_DIM 2048
#define E_EXP 64
#define TAU   2e-3f

typedef __bf16 bf16x8 __attribute__((ext_vector_type(8)));
typedef float  f32x16 __attribute__((ext_vector_type(16)));
typedef unsigned short ushort_t;

// workspace layout (bytes)
#define WS_WHI  0                    // ushort[32 chunks][512 slots][8] = 256KB, fragment-packed
#define WS_WLO  (256*1024)
#define WS_SUM  (512*1024)           // double[64] expert prob sums
#define WS_CNT  (512*1024 + 512)     // int flag count
#define WS_FLG  (512*1024 + 1024)    // int[T] flagged rows

__device__ __forceinline__ unsigned short bf16_rne(float x){
  unsigned int u = __float_as_uint(x);
  return (unsigned short)((u + 0x7FFFu + ((u >> 16) & 1u)) >> 16);
}

__device__ __forceinline__ void ins3(float& v1, int& i1, float& v2, int& i2,
                                     float& v3, int& i3, float v, int i){
  if (v > v1 || (v == v1 && i < i1)) { v3=v2; i3=i2; v2=v1; i2=i1; v1=v; i1=i; }
  else if (v > v2 || (v == v2 && i < i2)) { v3=v2; i3=i2; v2=v; i2=i; }
  else if (v > v3 || (v == v3 && i < i3)) { v3=v; i3=i; }
}

__device__ __forceinline__ void gload16(const void* g, const void* l){
  __builtin_amdgcn_global_load_lds(
      (const __attribute__((address_space(1))) unsigned int*)g,
      (__attribute__((address_space(3))) unsigned int*)l, 16, 0, 0);
}

// Pack W into chunk-fragment order: WHI[c][slot]*8 elems, slot s = (ks*2+nt)*64 + l,
// element = W[nt*32 + (l&31)][c*64 + ks*16 + (l>>5)*8 + j].  Main kernel then stages
// W with LINEAR global_load_lds and reads fragments at lane-consecutive addresses.
__global__ void wsplit_kernel(const float* __restrict__ W,
                              ushort_t* __restrict__ whi, ushort_t* __restrict__ wlo,
                              double* __restrict__ ESUM, int* __restrict__ FCNT){
  const int n = blockIdx.x * 256 + threadIdx.x;   // 64 blocks -> 16384 slots
  if (blockIdx.x == 0){
    if (threadIdx.x < 64) ESUM[threadIdx.x] = 0.0;
    else if (threadIdx.x == 64) *FCNT = 0;
  }
  const int c = n >> 9, s = n & 511;
  const int grp = s >> 6, l = s & 63;
  const int ks = grp >> 1, nt = grp & 1;
  const int m = l & 31, kg = l >> 5;
  const float* src = W + (size_t)(nt*32 + m)*D_DIM + c*64 + ks*16 + kg*8;
  float4 w0 = *reinterpret_cast<const float4*>(src);
  float4 w1 = *reinterpret_cast<const float4*>(src + 4);
  float f[8] = {w0.x,w0.y,w0.z,w0.w,w1.x,w1.y,w1.z,w1.w};
  unsigned h[8], lo[8];
  #pragma unroll
  for (int i = 0; i < 8; ++i){
    h[i]  = bf16_rne(f[i]);
    lo[i] = bf16_rne(f[i] - __uint_as_float(h[i] << 16));
  }
  uint4 hv = { h[0]|(h[1]<<16),  h[2]|(h[3]<<16),  h[4]|(h[5]<<16),  h[6]|(h[7]<<16) };
  uint4 lv = { lo[0]|(lo[1]<<16), lo[2]|(lo[3]<<16), lo[4]|(lo[5]<<16), lo[6]|(lo[7]<<16) };
  *reinterpret_cast<uint4*>(whi + (size_t)n*8) = hv;
  *reinterpret_cast<uint4*>(wlo + (size_t)n*8) = lv;
}

// Main fused kernel. Tile 32 rows x 64 experts, BK=64 f32 per chunk, 32 chunks.
// Triple-buffered LDS (3 x 24KB: X-f32 8KB | Whi 8KB | Wlo 8KB), all staging via
// global_load_lds; counted vmcnt(12) keeps 2 chunks permanently in flight.
// X LDS uses source-side XOR swizzle (16B granule ^ (row&15)); W is fragment-packed.
__launch_bounds__(256, 2)
__global__ void moe_main(const float* __restrict__ X, const float* __restrict__ NZ,
                         const ushort_t* __restrict__ WHI, const ushort_t* __restrict__ WLO,
                         const float* __restrict__ NW, float* __restrict__ OUT,
                         double* __restrict__ ESUM, int* __restrict__ FCNT,
                         int* __restrict__ FLIST)
{
  __shared__ __align__(16) char smem[73728];

  const int tid  = threadIdx.x;
  const int lane = tid & 63;
  const int wv   = tid >> 6;   // 0..3
  const int nt   = wv & 1;     // expert half
  const int kh   = wv >> 1;    // k half of chunk
  const int r0   = blockIdx.x << 5;
  const int m    = lane & 31;
  const int kg   = lane >> 5;

  // staging source pointers (per-lane, chunk-invariant part)
  const int ga  = wv*64 + lane;            // X granule for issue q=0
  const int rA  = ga >> 4, gxp = ga & 15;
  const int gxA = gxp ^ (rA & 15);         // source-side swizzle
  const char* px0 = (const char*)X + ((size_t)(r0 + rA)*D_DIM + gxA*4) * 4;
  const char* px1 = px0 + (size_t)16*D_DIM*4;      // rows r+16: same swizzle (r&15 equal)
  const char* pwh = (const char*)WHI + (size_t)(wv*64 + lane)*16;
  const char* pwl = (const char*)WLO + (size_t)(wv*64 + lane)*16;

  f32x16 acc;
  #pragma unroll
  for (int i = 0; i < 16; ++i) acc[i] = 0.0f;

  #define ISSUE(c, Boff) do{                                                   \
    const size_t xo = (size_t)(c)*256, wo = (size_t)(c)*8192;                  \
    gload16(px0 + xo,        smem + (Boff) +          wv*1024);                \
    gload16(px1 + xo,        smem + (Boff) +       (wv+4)*1024);               \
    gload16(pwh + wo,        smem + (Boff) + 8192  +  wv*1024);                \
    gload16(pwh + wo + 4096, smem + (Boff) + 8192  + (wv+4)*1024);             \
    gload16(pwl + wo,        smem + (Boff) + 16384 +  wv*1024);                \
    gload16(pwl + wo + 4096, smem + (Boff) + 16384 + (wv+4)*1024);             \
  }while(0)

  #define COMPUTE(Boff) do{                                                    \
    const char* Bp = smem + (Boff);                                            \
    _Pragma("unroll")                                                          \
    for (int ks2 = 0; ks2 < 2; ++ks2){                                         \
      const int ks = kh*2 + ks2;                                               \
      float4 fa = *reinterpret_cast<const float4*>(Bp + m*256 + (((ks*4+kg*2  ) ^ (m&15))<<4)); \
      float4 fb = *reinterpret_cast<const float4*>(Bp + m*256 + (((ks*4+kg*2+1) ^ (m&15))<<4)); \
      bf16x8 bh = *reinterpret_cast<const bf16x8*>(Bp + 8192  + ((((ks<<1)|nt)<<10) | (lane<<4))); \
      bf16x8 bl = *reinterpret_cast<const bf16x8*>(Bp + 16384 + ((((ks<<1)|nt)<<10) | (lane<<4))); \
      float fv[8] = {fa.x,fa.y,fa.z,fa.w,fb.x,fb.y,fb.z,fb.w};                 \
      bf16x8 ah, al;                                                           \
      _Pragma("unroll")                                                        \
      for (int ii = 0; ii < 8; ++ii){                                          \
        __bf16 hh = (__bf16)fv[ii];                                            \
        ah[ii] = hh; al[ii] = (__bf16)(fv[ii] - (float)hh);                    \
      }                                                                        \
      acc = __builtin_amdgcn_mfma_f32_32x32x16_bf16(ah, bh, acc, 0, 0, 0);     \
      acc = __builtin_amdgcn_mfma_f32_32x32x16_bf16(ah, bl, acc, 0, 0, 0);     \
      acc = __builtin_amdgcn_mfma_f32_32x32x16_bf16(al, bh, acc, 0, 0, 0);     \
    }                                                                          \
  }while(0)

  #define WAITV(n) do{ asm volatile("s_waitcnt vmcnt(" #n ")" ::: "memory");   \
                       __builtin_amdgcn_sched_barrier(0); }while(0)

  // prologue: 3 chunks in flight (18 issues/thread)
  ISSUE(0, 0); ISSUE(1, 24576); ISSUE(2, 49152);

  #pragma unroll 1
  for (int g = 0; g < 10; ++g){
    const int c = g*3;
    WAITV(12); __builtin_amdgcn_s_barrier();
    COMPUTE(0);
    __builtin_amdgcn_s_barrier();
    if (c < 29) ISSUE(c+3, 0);
    WAITV(12); __builtin_amdgcn_s_barrier();
    COMPUTE(24576);
    __builtin_amdgcn_s_barrier();
    if (c+1 < 29) ISSUE(c+4, 24576);
    WAITV(12); __builtin_amdgcn_s_barrier();
    COMPUTE(49152);
    __builtin_amdgcn_s_barrier();
    if (c+2 < 29) ISSUE(c+5, 49152);
  }
  // chunk 30 (buf0), chunk 31 (buf1)
  WAITV(6);  __builtin_amdgcn_s_barrier();
  COMPUTE(0);
  __builtin_amdgcn_s_barrier();
  WAITV(0);  __builtin_amdgcn_s_barrier();
  COMPUTE(24576);

  #undef ISSUE
  #undef COMPUTE
  #undef WAITV

  // ---- epilogue (regions avoid buf1 = [24576,49152) until all compute done) ----
  float* lgts = (float*)(smem);            // [32][64]  (buf0: consumed)
  float* nzs  = (float*)(smem + 8192);     // [32][64]
  float* prb  = (float*)(smem + 16384);    // [32][64]
  float* nws  = (float*)(smem + 49152);    // [64]      (buf2: consumed)
  const int ex = nt*32 + m;

  if (kh == 0){
    #pragma unroll
    for (int r = 0; r < 16; ++r){
      int rr = (r & 3) + ((r >> 2) << 3) + (kg << 2);   // verified 32x32 C/D layout
      lgts[rr*64 + ex] = acc[r];
    }
  }
  __syncthreads();
  if (kh == 1){
    #pragma unroll
    for (int r = 0; r < 16; ++r){
      int rr = (r & 3) + ((r >> 2) << 3) + (kg << 2);
      lgts[rr*64 + ex] += acc[r];
    }
  }
  const int sr = tid >> 3, sc = tid & 7;
  {
    *reinterpret_cast<float4*>(&nzs[sr*64 + sc*8]) =
      *reinterpret_cast<const float4*>(NZ + (size_t)(r0 + sr)*E_EXP + sc*8);
    *reinterpret_cast<float4*>(&nzs[sr*64 + sc*8 + 4]) =
      *reinterpret_cast<const float4*>(NZ + (size_t)(r0 + sr)*E_EXP + sc*8 + 4);
  }
  if (tid < 64) nws[tid] = NW[tid];
  __syncthreads();

  // gating: 8 lanes per row, 8 experts per lane (4 waves -> 32 rows)
  {
    const int rrow = (wv << 3) + (lane >> 3);
    const int j    = lane & 7;
    const int trow = r0 + rrow;
    float cl[8];
    float v1 = -INFINITY, v2 = -INFINITY, v3 = -INFINITY;
    int   i1 = 1 << 29,   i2 = 1 << 29,   i3 = 1 << 29;
    #pragma unroll
    for (int mm = 0; mm < 8; ++mm){
      int q = j + (mm << 3);
      float lg = lgts[rrow*64 + q];
      cl[mm] = lg;
      float vn = fmaf(nzs[rrow*64 + q], nws[q], lg);   // NOISY_STD = 1
      ins3(v1,i1,v2,i2,v3,i3, vn, q);
    }
    #pragma unroll
    for (int d = 1; d < 8; d <<= 1){
      float ov1 = __shfl_xor(v1, d, 8), ov2 = __shfl_xor(v2, d, 8), ov3 = __shfl_xor(v3, d, 8);
      int   oi1 = __shfl_xor(i1, d, 8), oi2 = __shfl_xor(i2, d, 8), oi3 = __shfl_xor(i3, d, 8);
      ins3(v1,i1,v2,i2,v3,i3, ov1, oi1);
      ins3(v1,i1,v2,i2,v3,i3, ov2, oi2);
      ins3(v1,i1,v2,i2,v3,i3, ov3, oi3);
    }
    float e1 = expf(v2 - v1);
    float g0 = 1.0f / (1.0f + e1);
    float g1 = e1 * g0;

    float mx = cl[0];
    #pragma unroll
    for (int mm = 1; mm < 8; ++mm) mx = fmaxf(mx, cl[mm]);
    #pragma unroll
    for (int d = 1; d < 8; d <<= 1) mx = fmaxf(mx, __shfl_xor(mx, d, 8));
    float sum = 0.0f, exv[8];
    #pragma unroll
    for (int mm = 0; mm < 8; ++mm){ exv[mm] = expf(cl[mm] - mx); sum += exv[mm]; }
    #pragma unroll
    for (int d = 1; d < 8; d <<= 1) sum += __shfl_xor(sum, d, 8);
    float inv = 1.0f / sum;
    #pragma unroll
    for (int mm = 0; mm < 8; ++mm) prb[rrow*64 + j + (mm << 3)] = exv[mm] * inv;

    if (j == 0){
      OUT[(size_t)T_TOK*E_EXP + (size_t)trow*2]     = (float)i1;
      OUT[(size_t)T_TOK*E_EXP + (size_t)trow*2 + 1] = (float)i2;
      if ((v1 - v2 < TAU) || (v2 - v3 < TAU)){   // near-tie -> fp64 fixup
        int slot = atomicAdd(FCNT, 1);
        FLIST[slot] = trow;
      }
    }
    #pragma unroll
    for (int mm = 0; mm < 8; ++mm){
      int q = j + (mm << 3);
      lgts[rrow*64 + q] = (q == i1) ? g0 : ((q == i2) ? g1 : 0.0f);
    }
  }
  __syncthreads();

  {
    *reinterpret_cast<float4*>(OUT + (size_t)(r0 + sr)*E_EXP + sc*8) =
      *reinterpret_cast<const float4*>(&lgts[sr*64 + sc*8]);
    *reinterpret_cast<float4*>(OUT + (size_t)(r0 + sr)*E_EXP + sc*8 + 4) =
      *reinterpret_cast<const float4*>(&lgts[sr*64 + sc*8 + 4]);
  }
  if (tid < 64){
    float s0 = 0.0f;
    #pragma unroll 8
    for (int rr2 = 0; rr2 < 32; ++rr2) s0 += prb[rr2*64 + tid];
    atomicAdd(&ESUM[tid], (double)s0);
  }
}

// fp64-exact recompute of flagged (near-tie) rows; coalesced, one block/row.
__launch_bounds__(256)
__global__ void moe_fixup(const float* __restrict__ X, const float* __restrict__ NZ,
                          const float* __restrict__ WG, const float* __restrict__ NW,
                          float* __restrict__ OUT, const int* __restrict__ FCNT,
                          const int* __restrict__ FLIST)
{
  __shared__ __align__(16) float xl[2048];
  __shared__ double lz[64];
  __shared__ int   si1, si2;
  __shared__ float sg0, sg1;
  const int n    = *FCNT;
  const int lane = threadIdx.x & 63;
  const int wv   = threadIdx.x >> 6;
  for (int idx = blockIdx.x; idx < n; idx += gridDim.x){
    const int t = FLIST[idx];
    {
      int off = threadIdx.x * 8;
      *reinterpret_cast<float4*>(xl + off) =
        *reinterpret_cast<const float4*>(X + (size_t)t*D_DIM + off);
      *reinterpret_cast<float4*>(xl + off + 4) =
        *reinterpret_cast<const float4*>(X + (size_t)t*D_DIM + off + 4);
    }
    __syncthreads();
    for (int s = 0; s < 16; ++s){
      const int e = wv*16 + s;
      const float* wr = WG + (size_t)e*D_DIM;
      double acc = 0.0;
      #pragma unroll
      for (int it = 0; it < 8; ++it){
        float4 w4 = *reinterpret_cast<const float4*>(wr + it*256 + lane*4);
        float4 x4 = *reinterpret_cast<const float4*>(xl + it*256 + lane*4);
        acc += (double)x4.x * (double)w4.x;
        acc += (double)x4.y * (double)w4.y;
        acc += (double)x4.z * (double)w4.z;
        acc += (double)x4.w * (double)w4.w;
      }
      #pragma unroll
      for (int off = 1; off < 64; off <<= 1) acc += __shfl_xor(acc, off, 64);
      if (lane == 0)
        lz[e] = acc + (double)NZ[(size_t)t*E_EXP + e] * (double)NW[e];
    }
    __syncthreads();
    if (threadIdx.x == 0){
      double b1 = -1e300, b2 = -1e300; int j1 = 0, j2 = 0;
      for (int q = 0; q < 64; ++q){
        double v = lz[q];
        if (v > b1){ b2 = b1; j2 = j1; b1 = v; j1 = q; }
        else if (v > b2){ b2 = v; j2 = q; }
      }
      double ee = exp(b2 - b1);
      sg0 = (float)(1.0 / (1.0 + ee));
      sg1 = (float)(ee / (1.0 + ee));
      si1 = j1; si2 = j2;
      OUT[(size_t)T_TOK*E_EXP + (size_t)t*2]     = (float)j1;
      OUT[(size_t)T_TOK*E_EXP + (size_t)t*2 + 1] = (float)j2;
    }
    __syncthreads();
    if (threadIdx.x < 64)
      OUT[(size_t)t*E_EXP + threadIdx.x] = (threadIdx.x == si1) ? sg0 :
                                           ((threadIdx.x == si2) ? sg1 : 0.0f);
    __syncthreads();
  }
}

__global__ void moe_loss(const double* __restrict__ ESUM, float* __restrict__ OUT){
  const int e = threadIdx.x;   // 64 threads
  double d = ESUM[e] * (1.0 / T_TOK) - (1.0 / 64.0);
  double sq = d * d;
  #pragma unroll
  for (int off = 1; off < 64; off <<= 1) sq += __shfl_xor(sq, off, 64);
  if (e == 0) OUT[(size_t)T_TOK*E_EXP + T_TOK*2] = (float)(sq * (0.01 / 64.0));
}

extern "C" void kernel_launch(void* const* d_in, const int* in_sizes, int n_in,
                              void* d_out, int out_size, void* d_ws, size_t ws_size,
                              hipStream_t stream)
{
  const float* X  = (const float*)d_in[0];
  const float* NZ = (const float*)d_in[1];
  const float* WG = (const float*)d_in[2];
  const float* NW = (const float*)d_in[3];
  float* OUT = (float*)d_out;
  char*  ws  = (char*)d_ws;
  ushort_t* WHI = (ushort_t*)(ws + WS_WHI);
  ushort_t* WLO = (ushort_t*)(ws + WS_WLO);
  double* ESUM = (double*)(ws + WS_SUM);
  int* FCNT  = (int*)(ws + WS_CNT);
  int* FLIST = (int*)(ws + WS_FLG);

  wsplit_kernel<<<dim3(64), dim3(256), 0, stream>>>(WG, WHI, WLO, ESUM, FCNT);
  moe_main<<<dim3(T_TOK/32), dim3(256), 0, stream>>>(X, NZ, WHI, WLO, NW, OUT, ESUM, FCNT, FLIST);
  moe_fixup<<<dim3(512), dim3(256), 0, stream>>>(X, NZ, WG, NW, OUT, FCNT, FLIST);
  moe_loss<<<dim3(1), dim3(64), 0, stream>>>(ESUM, OUT);
}

// Round 5
// 113.116 us; speedup vs baseline: 2.1264x; 1.0112x over previous
//
#include <hip/hip_runtime.h>
#include <hip/hip_bf16.h>

#define T_TOK 16384
#define D_DIM 2048
#define E_EXP 64
#define TAU   2e-3f

typedef __bf16 bf16x8 __attribute__((ext_vector_type(8)));
typedef float  f32x16 __attribute__((ext_vector_type(16)));
typedef unsigned short ushort_t;

// workspace layout (bytes)
#define WS_WHI  0                    // ushort[16 chunks][1024 granule-slots][8] = 256KB, fragment-packed
#define WS_WLO  (256*1024)
#define WS_SUM  (512*1024)           // double[64] expert prob sums
#define WS_CNT  (512*1024 + 512)     // int flag count
#define WS_FLG  (512*1024 + 1024)    // int[T] flagged rows

__device__ __forceinline__ unsigned short bf16_rne(float x){
  unsigned int u = __float_as_uint(x);
  return (unsigned short)((u + 0x7FFFu + ((u >> 16) & 1u)) >> 16);
}

__device__ __forceinline__ void ins3(float& v1, int& i1, float& v2, int& i2,
                                     float& v3, int& i3, float v, int i){
  if (v > v1 || (v == v1 && i < i1)) { v3=v2; i3=i2; v2=v1; i2=i1; v1=v; i1=i; }
  else if (v > v2 || (v == v2 && i < i2)) { v3=v2; i3=i2; v2=v; i2=i; }
  else if (v > v3 || (v == v3 && i < i3)) { v3=v; i3=i; }
}

__device__ __forceinline__ void gload16(const void* g, const void* l){
  __builtin_amdgcn_global_load_lds(
      (const __attribute__((address_space(1))) unsigned int*)g,
      (__attribute__((address_space(3))) unsigned int*)l, 16, 0, 0);
}

// Fragment-pack W, hi/lo bf16. Granule n = c*1024 + t*128 + eh*64 + lane holds
// 8 elems: W[eh*32 + (lane&31)][c*128 + t*16 + (lane>>5)*8 + j], j=0..7.
// Main kernel reads each wave's B-fragment as ONE lane-consecutive uint4 load.
__global__ void wsplit_kernel(const float* __restrict__ W,
                              ushort_t* __restrict__ whi, ushort_t* __restrict__ wlo,
                              double* __restrict__ ESUM, int* __restrict__ FCNT){
  const int n = blockIdx.x * 256 + threadIdx.x;   // 64 blocks -> 16384 granules
  if (blockIdx.x == 0){
    if (threadIdx.x < 64) ESUM[threadIdx.x] = 0.0;
    else if (threadIdx.x == 64) *FCNT = 0;
  }
  const int lane = n & 63;
  const int eh   = (n >> 6) & 1;
  const int t    = (n >> 7) & 7;
  const int c    = n >> 10;
  const float* src = W + (size_t)(eh*32 + (lane & 31))*D_DIM
                       + c*128 + t*16 + (lane >> 5)*8;
  float4 w0 = *reinterpret_cast<const float4*>(src);
  float4 w1 = *reinterpret_cast<const float4*>(src + 4);
  float f[8] = {w0.x,w0.y,w0.z,w0.w,w1.x,w1.y,w1.z,w1.w};
  unsigned h[8], lo[8];
  #pragma unroll
  for (int i = 0; i < 8; ++i){
    h[i]  = bf16_rne(f[i]);
    lo[i] = bf16_rne(f[i] - __uint_as_float(h[i] << 16));
  }
  uint4 hv = { h[0]|(h[1]<<16),  h[2]|(h[3]<<16),  h[4]|(h[5]<<16),  h[6]|(h[7]<<16) };
  uint4 lv = { lo[0]|(lo[1]<<16), lo[2]|(lo[3]<<16), lo[4]|(lo[5]<<16), lo[6]|(lo[7]<<16) };
  *reinterpret_cast<uint4*>(whi + (size_t)n*8) = hv;
  *reinterpret_cast<uint4*>(wlo + (size_t)n*8) = lv;
}

// Main fused kernel. Tile 32 rows x 64 experts x K=2048. 8 waves = (ks 0..3, eh 0..1).
// BK=128 -> 16 chunks. X: LDS double-buffer 2x16KB via global_load_lds with
// source-side granule swizzle g^(row&7). W: global->VGPR per wave (dbuf reg sets).
// Counted vmcnt(6) = one clump (2 X + 4 W) stays in flight across barriers.
__launch_bounds__(512, 4)
__global__ void moe_main(const float* __restrict__ X, const float* __restrict__ NZ,
                         const ushort_t* __restrict__ WHI, const ushort_t* __restrict__ WLO,
                         const float* __restrict__ NW, float* __restrict__ OUT,
                         double* __restrict__ ESUM, int* __restrict__ FCNT,
                         int* __restrict__ FLIST)
{
  __shared__ __align__(16) char smem[32768];

  const int tid  = threadIdx.x;
  const int lane = tid & 63;
  const int wv   = tid >> 6;   // 0..7
  const int eh   = wv & 1;     // expert half
  const int ks   = wv >> 1;    // K quarter of each chunk
  const int r0   = blockIdx.x << 5;
  const int m    = lane & 31;
  const int kg   = lane >> 5;

  // --- X staging addresses (per-lane source, wave-uniform LDS dst) ---
  const int n0   = wv*64 + lane;           // granule slot, issue 0 (rows 0..15)
  const int row0 = n0 >> 5, g0 = n0 & 31;
  const int gs0  = (g0 & 24) | ((g0 ^ row0) & 7);
  const char* px0 = (const char*)X + ((size_t)(r0 + row0)*D_DIM + gs0*4) * 4;
  const char* px1 = px0 + (size_t)16*D_DIM*4;   // rows 16..31, same swizzle (row&7 equal)
  const char* ldsx0 = smem +        wv*1024;    // wave-uniform
  const char* ldsx1 = smem + 8192 + wv*1024;

  // --- W fragment pointers (lane-consecutive 16B granules) ---
  const char* pwh = (const char*)WHI + (size_t)(ks*256 + eh*64 + lane)*16;
  const char* pwl = (const char*)WLO + (size_t)(ks*256 + eh*64 + lane)*16;

  // --- fragment-read LDS byte offsets (chunk-invariant) ---
  const int gf0 = ks*8 + kg*2;     // ks2=0 granule pair (gf0, gf0+1)
  const int gf1 = gf0 + 4;         // ks2=1
  const int offA0 = m*512 + (((gf0  ) & 24) | (((gf0  ) ^ m) & 7))*16;
  const int offB0 = m*512 + (((gf0+1) & 24) | (((gf0+1) ^ m) & 7))*16;
  const int offA1 = m*512 + (((gf1  ) & 24) | (((gf1  ) ^ m) & 7))*16;
  const int offB1 = m*512 + (((gf1+1) & 24) | (((gf1+1) ^ m) & 7))*16;

  f32x16 acc;
  #pragma unroll
  for (int i = 0; i < 16; ++i) acc[i] = 0.0f;

  uint4 whA0, wlA0, whA1, wlA1;   // W reg set A (even chunks)
  uint4 whB0, wlB0, whB1, wlB1;   // W reg set B (odd chunks)

  #define LOADW(c, H0, L0, H1, L1) do{                                         \
    H0 = *reinterpret_cast<const uint4*>(pwh + (size_t)(c)*16384);             \
    L0 = *reinterpret_cast<const uint4*>(pwl + (size_t)(c)*16384);             \
    H1 = *reinterpret_cast<const uint4*>(pwh + (size_t)(c)*16384 + 2048);      \
    L1 = *reinterpret_cast<const uint4*>(pwl + (size_t)(c)*16384 + 2048);      \
  }while(0)

  #define ISSUE(c, BUF, H0, L0, H1, L1) do{                                    \
    __builtin_amdgcn_sched_barrier(0);                                         \
    gload16(px0 + (size_t)(c)*512, ldsx0 + (BUF));                             \
    gload16(px1 + (size_t)(c)*512, ldsx1 + (BUF));                             \
    LOADW(c, H0, L0, H1, L1);                                                  \
    __builtin_amdgcn_sched_barrier(0);                                         \
  }while(0)

  #define CVT8(fa, fb, ah, al) do{                                             \
    float fv[8] = {fa.x,fa.y,fa.z,fa.w,fb.x,fb.y,fb.z,fb.w};                   \
    _Pragma("unroll")                                                          \
    for (int ii = 0; ii < 8; ++ii){                                            \
      __bf16 hh = (__bf16)fv[ii];                                              \
      ah[ii] = hh; al[ii] = (__bf16)(fv[ii] - (float)hh);                      \
    }                                                                          \
  }while(0)

  #define KS2(BUF, OA, OB, WH, WL) do{                                         \
    float4 fa = *reinterpret_cast<const float4*>(smem + (BUF) + (OA));         \
    float4 fb = *reinterpret_cast<const float4*>(smem + (BUF) + (OB));         \
    bf16x8 ah, al;                                                             \
    CVT8(fa, fb, ah, al);                                                      \
    bf16x8 bh = __builtin_bit_cast(bf16x8, WH);                                \
    bf16x8 bl = __builtin_bit_cast(bf16x8, WL);                                \
    acc = __builtin_amdgcn_mfma_f32_32x32x16_bf16(ah, bh, acc, 0, 0, 0);       \
    acc = __builtin_amdgcn_mfma_f32_32x32x16_bf16(ah, bl, acc, 0, 0, 0);       \
    acc = __builtin_amdgcn_mfma_f32_32x32x16_bf16(al, bh, acc, 0, 0, 0);       \
  }while(0)

  #define PHASE(cc, H0, L0, H1, L1, BUF, WNTOK, DOISS) do{                     \
    asm volatile("s_waitcnt vmcnt(" WNTOK ")" ::: "memory");                   \
    __builtin_amdgcn_sched_barrier(0);                                         \
    __builtin_amdgcn_s_barrier();                                              \
    KS2(BUF, offA0, offB0, H0, L0);                                            \
    KS2(BUF, offA1, offB1, H1, L1);                                            \
    __builtin_amdgcn_s_barrier();                                              \
    if (DOISS) ISSUE((cc) + 2, BUF, H0, L0, H1, L1);                           \
  }while(0)

  // prologue: clumps 0 (set A, buf0) and 1 (set B, buf1)
  ISSUE(0, 0,     whA0, wlA0, whA1, wlA1);
  ISSUE(1, 16384, whB0, wlB0, whB1, wlB1);
  // NOTE: ISSUE(c,...) loads X chunk c because px offsets use c directly; the
  // prologue calls pass c=0,1 -- adjust: ISSUE uses (c) for addresses, and in
  // PHASE we pass cc+2. Prologue above intentionally passes 0 and 1.

  #pragma unroll 1
  for (int g = 0; g < 7; ++g){
    PHASE(2*g,     whA0, wlA0, whA1, wlA1, 0,     "6", 1);
    PHASE(2*g + 1, whB0, wlB0, whB1, wlB1, 16384, "6", 1);
  }
  PHASE(14, whA0, wlA0, whA1, wlA1, 0,     "6", 0);
  PHASE(15, whB0, wlB0, whB1, wlB1, 16384, "0", 0);

  #undef PHASE
  #undef KS2
  #undef CVT8
  #undef ISSUE
  #undef LOADW

  // ---- epilogue: K-quarter reduction (deterministic 4-phase chain) ----
  float* lgts = (float*)(smem);            // [32][64]  (buf0, consumed)
  float* nzs  = (float*)(smem + 8192);     // [32][64]
  float* prb  = (float*)(smem + 16384);    // [32][64]  (buf1, consumed)
  float* nws  = (float*)(smem + 24576);    // [64]
  const int ex = eh*32 + m;

  __syncthreads();
  if (ks == 0){
    #pragma unroll
    for (int r = 0; r < 16; ++r){
      int rr = (r & 3) + ((r >> 2) << 3) + (kg << 2);   // verified 32x32 C/D layout
      lgts[rr*64 + ex] = acc[r];
    }
  }
  __syncthreads();
  #pragma unroll
  for (int p = 1; p < 4; ++p){
    if (ks == p){
      #pragma unroll
      for (int r = 0; r < 16; ++r){
        int rr = (r & 3) + ((r >> 2) << 3) + (kg << 2);
        lgts[rr*64 + ex] += acc[r];
      }
    }
    __syncthreads();
  }

  // stage noise + noise_weight
  const int sr = tid >> 4, sc = tid & 15;
  *reinterpret_cast<float4*>(&nzs[sr*64 + sc*4]) =
    *reinterpret_cast<const float4*>(NZ + (size_t)(r0 + sr)*E_EXP + sc*4);
  if (tid < 64) nws[tid] = NW[tid];
  __syncthreads();

  // gating: waves 0..3, 8 lanes per row, 8 experts per lane
  if (wv < 4){
    const int rrow = (wv << 3) + (lane >> 3);
    const int j    = lane & 7;
    const int trow = r0 + rrow;
    float cl[8];
    float v1 = -INFINITY, v2 = -INFINITY, v3 = -INFINITY;
    int   i1 = 1 << 29,   i2 = 1 << 29,   i3 = 1 << 29;
    #pragma unroll
    for (int mm = 0; mm < 8; ++mm){
      int q = j + (mm << 3);
      float lg = lgts[rrow*64 + q];
      cl[mm] = lg;
      float vn = fmaf(nzs[rrow*64 + q], nws[q], lg);   // NOISY_STD = 1
      ins3(v1,i1,v2,i2,v3,i3, vn, q);
    }
    #pragma unroll
    for (int d = 1; d < 8; d <<= 1){
      float ov1 = __shfl_xor(v1, d, 8), ov2 = __shfl_xor(v2, d, 8), ov3 = __shfl_xor(v3, d, 8);
      int   oi1 = __shfl_xor(i1, d, 8), oi2 = __shfl_xor(i2, d, 8), oi3 = __shfl_xor(i3, d, 8);
      ins3(v1,i1,v2,i2,v3,i3, ov1, oi1);
      ins3(v1,i1,v2,i2,v3,i3, ov2, oi2);
      ins3(v1,i1,v2,i2,v3,i3, ov3, oi3);
    }
    float e1 = expf(v2 - v1);
    float g0g = 1.0f / (1.0f + e1);
    float g1g = e1 * g0g;

    float mx = cl[0];
    #pragma unroll
    for (int mm = 1; mm < 8; ++mm) mx = fmaxf(mx, cl[mm]);
    #pragma unroll
    for (int d = 1; d < 8; d <<= 1) mx = fmaxf(mx, __shfl_xor(mx, d, 8));
    float sum = 0.0f, exv[8];
    #pragma unroll
    for (int mm = 0; mm < 8; ++mm){ exv[mm] = expf(cl[mm] - mx); sum += exv[mm]; }
    #pragma unroll
    for (int d = 1; d < 8; d <<= 1) sum += __shfl_xor(sum, d, 8);
    float inv = 1.0f / sum;
    #pragma unroll
    for (int mm = 0; mm < 8; ++mm) prb[rrow*64 + j + (mm << 3)] = exv[mm] * inv;

    if (j == 0){
      OUT[(size_t)T_TOK*E_EXP + (size_t)trow*2]     = (float)i1;
      OUT[(size_t)T_TOK*E_EXP + (size_t)trow*2 + 1] = (float)i2;
      if ((v1 - v2 < TAU) || (v2 - v3 < TAU)){   // near-tie -> fp64 fixup
        int slot = atomicAdd(FCNT, 1);
        FLIST[slot] = trow;
      }
    }
    #pragma unroll
    for (int mm = 0; mm < 8; ++mm){
      int q = j + (mm << 3);
      lgts[rrow*64 + q] = (q == i1) ? g0g : ((q == i2) ? g1g : 0.0f);
    }
  }
  __syncthreads();

  // coalesced gates write (512 threads x float4)
  *reinterpret_cast<float4*>(OUT + (size_t)(r0 + sr)*E_EXP + sc*4) =
    *reinterpret_cast<const float4*>(&lgts[sr*64 + sc*4]);
  // per-expert prob column sums -> one f64 atomic per expert per block
  if (tid < 64){
    float s0 = 0.0f;
    #pragma unroll 8
    for (int rr2 = 0; rr2 < 32; ++rr2) s0 += prb[rr2*64 + tid];
    atomicAdd(&ESUM[tid], (double)s0);
  }
}

// fp64-exact recompute of flagged (near-tie) rows; coalesced, one block/row.
__launch_bounds__(256)
__global__ void moe_fixup(const float* __restrict__ X, const float* __restrict__ NZ,
                          const float* __restrict__ WG, const float* __restrict__ NW,
                          float* __restrict__ OUT, const int* __restrict__ FCNT,
                          const int* __restrict__ FLIST)
{
  __shared__ __align__(16) float xl[2048];
  __shared__ double lz[64];
  __shared__ int   si1, si2;
  __shared__ float sg0, sg1;
  const int n    = *FCNT;
  const int lane = threadIdx.x & 63;
  const int wv   = threadIdx.x >> 6;
  for (int idx = blockIdx.x; idx < n; idx += gridDim.x){
    const int t = FLIST[idx];
    {
      int off = threadIdx.x * 8;
      *reinterpret_cast<float4*>(xl + off) =
        *reinterpret_cast<const float4*>(X + (size_t)t*D_DIM + off);
      *reinterpret_cast<float4*>(xl + off + 4) =
        *reinterpret_cast<const float4*>(X + (size_t)t*D_DIM + off + 4);
    }
    __syncthreads();
    for (int s = 0; s < 16; ++s){
      const int e = wv*16 + s;
      const float* wr = WG + (size_t)e*D_DIM;
      double acc = 0.0;
      #pragma unroll
      for (int it = 0; it < 8; ++it){
        float4 w4 = *reinterpret_cast<const float4*>(wr + it*256 + lane*4);
        float4 x4 = *reinterpret_cast<const float4*>(xl + it*256 + lane*4);
        acc += (double)x4.x * (double)w4.x;
        acc += (double)x4.y * (double)w4.y;
        acc += (double)x4.z * (double)w4.z;
        acc += (double)x4.w * (double)w4.w;
      }
      #pragma unroll
      for (int off = 1; off < 64; off <<= 1) acc += __shfl_xor(acc, off, 64);
      if (lane == 0)
        lz[e] = acc + (double)NZ[(size_t)t*E_EXP + e] * (double)NW[e];
    }
    __syncthreads();
    if (threadIdx.x == 0){
      double b1 = -1e300, b2 = -1e300; int j1 = 0, j2 = 0;
      for (int q = 0; q < 64; ++q){
        double v = lz[q];
        if (v > b1){ b2 = b1; j2 = j1; b1 = v; j1 = q; }
        else if (v > b2){ b2 = v; j2 = q; }
      }
      double ee = exp(b2 - b1);
      sg0 = (float)(1.0 / (1.0 + ee));
      sg1 = (float)(ee / (1.0 + ee));
      si1 = j1; si2 = j2;
      OUT[(size_t)T_TOK*E_EXP + (size_t)t*2]     = (float)j1;
      OUT[(size_t)T_TOK*E_EXP + (size_t)t*2 + 1] = (float)j2;
    }
    __syncthreads();
    if (threadIdx.x < 64)
      OUT[(size_t)t*E_EXP + threadIdx.x] = (threadIdx.x == si1) ? sg0 :
                                           ((threadIdx.x == si2) ? sg1 : 0.0f);
    __syncthreads();
  }
}

__global__ void moe_loss(const double* __restrict__ ESUM, float* __restrict__ OUT){
  const int e = threadIdx.x;   // 64 threads
  double d = ESUM[e] * (1.0 / T_TOK) - (1.0 / 64.0);
  double sq = d * d;
  #pragma unroll
  for (int off = 1; off < 64; off <<= 1) sq += __shfl_xor(sq, off, 64);
  if (e == 0) OUT[(size_t)T_TOK*E_EXP + T_TOK*2] = (float)(sq * (0.01 / 64.0));
}

extern "C" void kernel_launch(void* const* d_in, const int* in_sizes, int n_in,
                              void* d_out, int out_size, void* d_ws, size_t ws_size,
                              hipStream_t stream)
{
  const float* X  = (const float*)d_in[0];
  const float* NZ = (const float*)d_in[1];
  const float* WG = (const float*)d_in[2];
  const float* NW = (const float*)d_in[3];
  float* OUT = (float*)d_out;
  char*  ws  = (char*)d_ws;
  ushort_t* WHI = (ushort_t*)(ws + WS_WHI);
  ushort_t* WLO = (ushort_t*)(ws + WS_WLO);
  double* ESUM = (double*)(ws + WS_SUM);
  int* FCNT  = (int*)(ws + WS_CNT);
  int* FLIST = (int*)(ws + WS_FLG);

  wsplit_kernel<<<dim3(64), dim3(256), 0, stream>>>(WG, WHI, WLO, ESUM, FCNT);
  moe_main<<<dim3(T_TOK/32), dim3(512), 0, stream>>>(X, NZ, WHI, WLO, NW, OUT, ESUM, FCNT, FLIST);
  moe_fixup<<<dim3(512), dim3(256), 0, stream>>>(X, NZ, WG, NW, OUT, FCNT, FLIST);
  moe_loss<<<dim3(1), dim3(64), 0, stream>>>(ESUM, OUT);
}

// Round 6
// 105.557 us; speedup vs baseline: 2.2787x; 1.0716x over previous
//
#include <hip/hip_runtime.h>
#include <hip/hip_bf16.h>

#define T_TOK 16384
#define D_DIM 2048
#define E_EXP 64
#define TAU   2e-3f

typedef __bf16 bf16x8 __attribute__((ext_vector_type(8)));
typedef float  f32x16 __attribute__((ext_vector_type(16)));
typedef unsigned short ushort_t;

// workspace layout (bytes)
#define WS_WHI  0                    // ushort[16384 granules][8] = 256KB, fragment-packed
#define WS_WLO  (256*1024)
#define WS_SUM  (512*1024)           // double[64] expert prob sums
#define WS_CNT  (512*1024 + 512)     // int flag count
#define WS_FLG  (512*1024 + 1024)    // int[T] flagged rows

__device__ __forceinline__ unsigned short bf16_rne(float x){
  unsigned int u = __float_as_uint(x);
  return (unsigned short)((u + 0x7FFFu + ((u >> 16) & 1u)) >> 16);
}

__device__ __forceinline__ void ins3(float& v1, int& i1, float& v2, int& i2,
                                     float& v3, int& i3, float v, int i){
  if (v > v1 || (v == v1 && i < i1)) { v3=v2; i3=i2; v2=v1; i2=i1; v1=v; i1=i; }
  else if (v > v2 || (v == v2 && i < i2)) { v3=v2; i3=i2; v2=v; i2=i; }
  else if (v > v3 || (v == v3 && i < i3)) { v3=v; i3=i; }
}

__device__ __forceinline__ void gload16(const void* g, const void* l){
  __builtin_amdgcn_global_load_lds(
      (const __attribute__((address_space(1))) unsigned int*)g,
      (__attribute__((address_space(3))) unsigned int*)l, 16, 0, 0);
}

// Fragment-pack W hi/lo bf16. Granule gidx = c*1024 + ks*512 + t*128 + eh*64 + lane
// holds 8 elems: W[eh*32 + (lane&31)][c*128 + ks*64 + t*16 + (lane>>5)*8 + j].
// Reader (wave eh,ks) loads 1KB contiguous per (c,t) -> perfectly coalesced.
__global__ void wsplit_kernel(const float* __restrict__ W,
                              ushort_t* __restrict__ whi, ushort_t* __restrict__ wlo,
                              double* __restrict__ ESUM, int* __restrict__ FCNT){
  const int n = blockIdx.x * 256 + threadIdx.x;   // 64 blocks -> 16384 granules
  if (blockIdx.x == 0){
    if (threadIdx.x < 64) ESUM[threadIdx.x] = 0.0;
    else if (threadIdx.x == 64) *FCNT = 0;
  }
  const int e  = n >> 8;          // coalesced read side
  const int k0 = (n & 255) * 8;
  const float* src = W + (size_t)e*D_DIM + k0;
  float4 w0 = *reinterpret_cast<const float4*>(src);
  float4 w1 = *reinterpret_cast<const float4*>(src + 4);
  float f[8] = {w0.x,w0.y,w0.z,w0.w,w1.x,w1.y,w1.z,w1.w};
  unsigned h[8], lo[8];
  #pragma unroll
  for (int i = 0; i < 8; ++i){
    h[i]  = bf16_rne(f[i]);
    lo[i] = bf16_rne(f[i] - __uint_as_float(h[i] << 16));
  }
  uint4 hv = { h[0]|(h[1]<<16),  h[2]|(h[3]<<16),  h[4]|(h[5]<<16),  h[6]|(h[7]<<16) };
  uint4 lv = { lo[0]|(lo[1]<<16), lo[2]|(lo[3]<<16), lo[4]|(lo[5]<<16), lo[6]|(lo[7]<<16) };
  const int c  = k0 >> 7, ks = (k0 >> 6) & 1, t = (k0 >> 4) & 3, kg = (k0 >> 3) & 1;
  const int gidx = c*1024 + ks*512 + t*128 + (e >> 5)*64 + kg*32 + (e & 31);
  *reinterpret_cast<uint4*>(whi + (size_t)gidx*8) = hv;
  *reinterpret_cast<uint4*>(wlo + (size_t)gidx*8) = lv;
}

// Main fused kernel. Tile 64 rows x 64 experts, BK=128, 16 phases, grid 256 (1/CU).
// 8 waves = (mh, eh, ks). X: LDS 2x32KB dbuf via global_load_lds, involutive
// granule swizzle g<->(g&24)|((g^row)&7). W: global->VGPR, named dbuf reg sets.
// Counted vmcnt(12) = one clump (4 X-gload + 8 W-load) in flight across barriers.
__launch_bounds__(512, 1)
__global__ void moe_main(const float* __restrict__ X, const float* __restrict__ NZ,
                         const ushort_t* __restrict__ WHI, const ushort_t* __restrict__ WLO,
                         const float* __restrict__ NW, float* __restrict__ OUT,
                         double* __restrict__ ESUM, int* __restrict__ FCNT,
                         int* __restrict__ FLIST)
{
  __shared__ __align__(16) char smem[65792];

  const int tid  = threadIdx.x;
  const int lane = tid & 63;
  const int wv   = tid >> 6;        // 0..7
  const int eh   = wv & 1;          // expert half
  const int ks   = (wv >> 1) & 1;   // k half of chunk
  const int mh   = wv >> 2;         // row half
  const int r0   = blockIdx.x << 6;
  const int m    = lane & 31;
  const int kg   = lane >> 5;
  const int row  = mh*32 + m;

  // --- X gload source pointers (pre-swizzled per-lane), q = 0..3 ---
  const char* pq[4];
  #pragma unroll
  for (int q = 0; q < 4; ++q){
    const int rw = wv*8 + q*2 + (lane >> 5);
    const int gp = lane & 31;
    const int g  = (gp & 24) | ((gp ^ rw) & 7);
    pq[q] = (const char*)X + ((size_t)(r0 + rw)*D_DIM + g*4) * 4;
  }
  const char* pq0 = pq[0]; const char* pq1 = pq[1];
  const char* pq2 = pq[2]; const char* pq3 = pq[3];

  // --- W fragment pointers ---
  const char* pwh = (const char*)WHI + (size_t)(ks*512 + eh*64 + lane)*16;
  const char* pwl = (const char*)WLO + (size_t)(ks*512 + eh*64 + lane)*16;

  // --- X fragment LDS byte offsets (chunk-invariant) ---
  #define XOFF(t, h) (row*512 + ((((ks*16 + (t)*4 + kg*2 + (h)) & 24) | (((ks*16 + (t)*4 + kg*2 + (h)) ^ row) & 7)) << 4))
  const int xo00 = XOFF(0,0), xo01 = XOFF(0,1);
  const int xo10 = XOFF(1,0), xo11 = XOFF(1,1);
  const int xo20 = XOFF(2,0), xo21 = XOFF(2,1);
  const int xo30 = XOFF(3,0), xo31 = XOFF(3,1);
  #undef XOFF

  f32x16 acc;
  #pragma unroll
  for (int i = 0; i < 16; ++i) acc[i] = 0.0f;

  uint4 hA0,lA0,hA1,lA1,hA2,lA2,hA3,lA3;   // W set A (even chunks)
  uint4 hB0,lB0,hB1,lB1,hB2,lB2,hB3,lB3;   // W set B (odd chunks)

  #define ISSUE(c, BUF, H0,L0,H1,L1,H2,L2,H3,L3) do{                           \
    __builtin_amdgcn_sched_barrier(0);                                         \
    gload16(pq0 + (size_t)(c)*512, smem + (BUF) + wv*4096);                    \
    gload16(pq1 + (size_t)(c)*512, smem + (BUF) + wv*4096 + 1024);             \
    gload16(pq2 + (size_t)(c)*512, smem + (BUF) + wv*4096 + 2048);             \
    gload16(pq3 + (size_t)(c)*512, smem + (BUF) + wv*4096 + 3072);             \
    H0 = *reinterpret_cast<const uint4*>(pwh + (size_t)(c)*16384);             \
    L0 = *reinterpret_cast<const uint4*>(pwl + (size_t)(c)*16384);             \
    H1 = *reinterpret_cast<const uint4*>(pwh + (size_t)(c)*16384 + 2048);      \
    L1 = *reinterpret_cast<const uint4*>(pwl + (size_t)(c)*16384 + 2048);      \
    H2 = *reinterpret_cast<const uint4*>(pwh + (size_t)(c)*16384 + 4096);      \
    L2 = *reinterpret_cast<const uint4*>(pwl + (size_t)(c)*16384 + 4096);      \
    H3 = *reinterpret_cast<const uint4*>(pwh + (size_t)(c)*16384 + 6144);      \
    L3 = *reinterpret_cast<const uint4*>(pwl + (size_t)(c)*16384 + 6144);      \
    __builtin_amdgcn_sched_barrier(0);                                         \
  }while(0)

  #define KSTEP(BUF, OA, OB, WH, WL) do{                                       \
    float4 fa = *reinterpret_cast<const float4*>(smem + (BUF) + (OA));         \
    float4 fb = *reinterpret_cast<const float4*>(smem + (BUF) + (OB));         \
    bf16x8 ah, al;                                                             \
    { float fv[8] = {fa.x,fa.y,fa.z,fa.w,fb.x,fb.y,fb.z,fb.w};                 \
      _Pragma("unroll")                                                        \
      for (int ii = 0; ii < 8; ++ii){                                          \
        __bf16 hh = (__bf16)fv[ii];                                            \
        ah[ii] = hh; al[ii] = (__bf16)(fv[ii] - (float)hh);                    \
      } }                                                                      \
    bf16x8 bh = __builtin_bit_cast(bf16x8, WH);                                \
    bf16x8 bl = __builtin_bit_cast(bf16x8, WL);                                \
    acc = __builtin_amdgcn_mfma_f32_32x32x16_bf16(ah, bh, acc, 0, 0, 0);       \
    acc = __builtin_amdgcn_mfma_f32_32x32x16_bf16(ah, bl, acc, 0, 0, 0);       \
    acc = __builtin_amdgcn_mfma_f32_32x32x16_bf16(al, bh, acc, 0, 0, 0);       \
  }while(0)

  #define COMPUTE(BUF, H0,L0,H1,L1,H2,L2,H3,L3) do{                            \
    KSTEP(BUF, xo00, xo01, H0, L0);                                            \
    KSTEP(BUF, xo10, xo11, H1, L1);                                            \
    KSTEP(BUF, xo20, xo21, H2, L2);                                            \
    KSTEP(BUF, xo30, xo31, H3, L3);                                            \
  }while(0)

  #define WAITV(N) do{ asm volatile("s_waitcnt vmcnt(" #N ")" ::: "memory");   \
                       __builtin_amdgcn_sched_barrier(0); }while(0)

  // prologue: chunks 0 (buf0/setA) and 1 (buf1/setB) in flight
  ISSUE(0, 0,     hA0,lA0,hA1,lA1,hA2,lA2,hA3,lA3);
  ISSUE(1, 32768, hB0,lB0,hB1,lB1,hB2,lB2,hB3,lB3);

  #pragma unroll 1
  for (int g = 0; g < 7; ++g){
    const int c = 2*g;
    WAITV(12); __builtin_amdgcn_s_barrier();
    COMPUTE(0, hA0,lA0,hA1,lA1,hA2,lA2,hA3,lA3);
    __builtin_amdgcn_s_barrier();
    ISSUE(c+2, 0, hA0,lA0,hA1,lA1,hA2,lA2,hA3,lA3);
    WAITV(12); __builtin_amdgcn_s_barrier();
    COMPUTE(32768, hB0,lB0,hB1,lB1,hB2,lB2,hB3,lB3);
    __builtin_amdgcn_s_barrier();
    ISSUE(c+3, 32768, hB0,lB0,hB1,lB1,hB2,lB2,hB3,lB3);
  }
  // phases 14, 15 (no further issue)
  WAITV(12); __builtin_amdgcn_s_barrier();
  COMPUTE(0, hA0,lA0,hA1,lA1,hA2,lA2,hA3,lA3);
  __builtin_amdgcn_s_barrier();
  WAITV(0);  __builtin_amdgcn_s_barrier();
  COMPUTE(32768, hB0,lB0,hB1,lB1,hB2,lB2,hB3,lB3);

  #undef ISSUE
  #undef KSTEP
  #undef COMPUTE
  #undef WAITV

  // ---- epilogue ----
  float* lgts = (float*)(smem);            // [64][64] = 16KB
  float* nzs  = (float*)(smem + 16384);    // [64][64]
  float* prb  = (float*)(smem + 32768);    // [64][64]
  float* red  = (float*)(smem + 49152);    // [64][64] ks=1 partials
  float* nws  = (float*)(smem + 65536);    // [64]
  const int ex = eh*32 + m;

  __syncthreads();
  if (ks == 1){
    #pragma unroll
    for (int r = 0; r < 16; ++r){
      int rr = (r & 3) + ((r >> 2) << 3) + (kg << 2);   // verified 32x32 C/D layout
      red[(mh*32 + rr)*64 + ex] = acc[r];
    }
  }
  __syncthreads();
  if (ks == 0){
    #pragma unroll
    for (int r = 0; r < 16; ++r){
      int rr = (r & 3) + ((r >> 2) << 3) + (kg << 2);
      int idx = (mh*32 + rr)*64 + ex;
      lgts[idx] = acc[r] + red[idx];
    }
  }
  // stage noise + noise_weight (512 threads x 8 floats)
  {
    const int rw = tid >> 3, cb = (tid & 7) * 8;
    *reinterpret_cast<float4*>(&nzs[rw*64 + cb]) =
      *reinterpret_cast<const float4*>(NZ + (size_t)(r0 + rw)*E_EXP + cb);
    *reinterpret_cast<float4*>(&nzs[rw*64 + cb + 4]) =
      *reinterpret_cast<const float4*>(NZ + (size_t)(r0 + rw)*E_EXP + cb + 4);
  }
  if (tid < 64) nws[tid] = NW[tid];
  __syncthreads();

  // gating: 8 waves x 8 rows, 8 lanes per row, 8 experts per lane
  {
    const int rrow = (wv << 3) + (lane >> 3);
    const int j    = lane & 7;
    const int trow = r0 + rrow;
    float cl[8];
    float v1 = -INFINITY, v2 = -INFINITY, v3 = -INFINITY;
    int   i1 = 1 << 29,   i2 = 1 << 29,   i3 = 1 << 29;
    #pragma unroll
    for (int mm = 0; mm < 8; ++mm){
      int q = j + (mm << 3);
      float lg = lgts[rrow*64 + q];
      cl[mm] = lg;
      float vn = fmaf(nzs[rrow*64 + q], nws[q], lg);   // NOISY_STD = 1
      ins3(v1,i1,v2,i2,v3,i3, vn, q);
    }
    #pragma unroll
    for (int d = 1; d < 8; d <<= 1){
      float ov1 = __shfl_xor(v1, d, 8), ov2 = __shfl_xor(v2, d, 8), ov3 = __shfl_xor(v3, d, 8);
      int   oi1 = __shfl_xor(i1, d, 8), oi2 = __shfl_xor(i2, d, 8), oi3 = __shfl_xor(i3, d, 8);
      ins3(v1,i1,v2,i2,v3,i3, ov1, oi1);
      ins3(v1,i1,v2,i2,v3,i3, ov2, oi2);
      ins3(v1,i1,v2,i2,v3,i3, ov3, oi3);
    }
    float e1 = expf(v2 - v1);
    float g0g = 1.0f / (1.0f + e1);
    float g1g = e1 * g0g;

    float mx = cl[0];
    #pragma unroll
    for (int mm = 1; mm < 8; ++mm) mx = fmaxf(mx, cl[mm]);
    #pragma unroll
    for (int d = 1; d < 8; d <<= 1) mx = fmaxf(mx, __shfl_xor(mx, d, 8));
    float sum = 0.0f, exv[8];
    #pragma unroll
    for (int mm = 0; mm < 8; ++mm){ exv[mm] = expf(cl[mm] - mx); sum += exv[mm]; }
    #pragma unroll
    for (int d = 1; d < 8; d <<= 1) sum += __shfl_xor(sum, d, 8);
    float inv = 1.0f / sum;
    #pragma unroll
    for (int mm = 0; mm < 8; ++mm) prb[rrow*64 + j + (mm << 3)] = exv[mm] * inv;

    if (j == 0){
      OUT[(size_t)T_TOK*E_EXP + (size_t)trow*2]     = (float)i1;
      OUT[(size_t)T_TOK*E_EXP + (size_t)trow*2 + 1] = (float)i2;
      if ((v1 - v2 < TAU) || (v2 - v3 < TAU)){   // near-tie -> fp64 fixup
        int slot = atomicAdd(FCNT, 1);
        FLIST[slot] = trow;
      }
    }
    #pragma unroll
    for (int mm = 0; mm < 8; ++mm){
      int q = j + (mm << 3);
      lgts[rrow*64 + q] = (q == i1) ? g0g : ((q == i2) ? g1g : 0.0f);
    }
  }
  __syncthreads();

  // coalesced gates write
  {
    const int rw = tid >> 3, cb = (tid & 7) * 8;
    *reinterpret_cast<float4*>(OUT + (size_t)(r0 + rw)*E_EXP + cb) =
      *reinterpret_cast<const float4*>(&lgts[rw*64 + cb]);
    *reinterpret_cast<float4*>(OUT + (size_t)(r0 + rw)*E_EXP + cb + 4) =
      *reinterpret_cast<const float4*>(&lgts[rw*64 + cb + 4]);
  }
  // per-expert prob column sums -> one f64 atomic per expert per block
  if (tid < 64){
    float s0 = 0.0f;
    #pragma unroll 8
    for (int rr2 = 0; rr2 < 64; ++rr2) s0 += prb[rr2*64 + tid];
    atomicAdd(&ESUM[tid], (double)s0);
  }
}

// fp64-exact recompute of flagged (near-tie) rows; coalesced, one block/row.
__launch_bounds__(256)
__global__ void moe_fixup(const float* __restrict__ X, const float* __restrict__ NZ,
                          const float* __restrict__ WG, const float* __restrict__ NW,
                          float* __restrict__ OUT, const int* __restrict__ FCNT,
                          const int* __restrict__ FLIST)
{
  __shared__ __align__(16) float xl[2048];
  __shared__ double lz[64];
  __shared__ int   si1, si2;
  __shared__ float sg0, sg1;
  const int n    = *FCNT;
  const int lane = threadIdx.x & 63;
  const int wv   = threadIdx.x >> 6;
  for (int idx = blockIdx.x; idx < n; idx += gridDim.x){
    const int t = FLIST[idx];
    {
      int off = threadIdx.x * 8;
      *reinterpret_cast<float4*>(xl + off) =
        *reinterpret_cast<const float4*>(X + (size_t)t*D_DIM + off);
      *reinterpret_cast<float4*>(xl + off + 4) =
        *reinterpret_cast<const float4*>(X + (size_t)t*D_DIM + off + 4);
    }
    __syncthreads();
    for (int s = 0; s < 16; ++s){
      const int e = wv*16 + s;
      const float* wr = WG + (size_t)e*D_DIM;
      double acc = 0.0;
      #pragma unroll
      for (int it = 0; it < 8; ++it){
        float4 w4 = *reinterpret_cast<const float4*>(wr + it*256 + lane*4);
        float4 x4 = *reinterpret_cast<const float4*>(xl + it*256 + lane*4);
        acc += (double)x4.x * (double)w4.x;
        acc += (double)x4.y * (double)w4.y;
        acc += (double)x4.z * (double)w4.z;
        acc += (double)x4.w * (double)w4.w;
      }
      #pragma unroll
      for (int off = 1; off < 64; off <<= 1) acc += __shfl_xor(acc, off, 64);
      if (lane == 0)
        lz[e] = acc + (double)NZ[(size_t)t*E_EXP + e] * (double)NW[e];
    }
    __syncthreads();
    if (threadIdx.x == 0){
      double b1 = -1e300, b2 = -1e300; int j1 = 0, j2 = 0;
      for (int q = 0; q < 64; ++q){
        double v = lz[q];
        if (v > b1){ b2 = b1; j2 = j1; b1 = v; j1 = q; }
        else if (v > b2){ b2 = v; j2 = q; }
      }
      double ee = exp(b2 - b1);
      sg0 = (float)(1.0 / (1.0 + ee));
      sg1 = (float)(ee / (1.0 + ee));
      si1 = j1; si2 = j2;
      OUT[(size_t)T_TOK*E_EXP + (size_t)t*2]     = (float)j1;
      OUT[(size_t)T_TOK*E_EXP + (size_t)t*2 + 1] = (float)j2;
    }
    __syncthreads();
    if (threadIdx.x < 64)
      OUT[(size_t)t*E_EXP + threadIdx.x] = (threadIdx.x == si1) ? sg0 :
                                           ((threadIdx.x == si2) ? sg1 : 0.0f);
    __syncthreads();
  }
}

__global__ void moe_loss(const double* __restrict__ ESUM, float* __restrict__ OUT){
  const int e = threadIdx.x;   // 64 threads
  double d = ESUM[e] * (1.0 / T_TOK) - (1.0 / 64.0);
  double sq = d * d;
  #pragma unroll
  for (int off = 1; off < 64; off <<= 1) sq += __shfl_xor(sq, off, 64);
  if (e == 0) OUT[(size_t)T_TOK*E_EXP + T_TOK*2] = (float)(sq * (0.01 / 64.0));
}

extern "C" void kernel_launch(void* const* d_in, const int* in_sizes, int n_in,
                              void* d_out, int out_size, void* d_ws, size_t ws_size,
                              hipStream_t stream)
{
  const float* X  = (const float*)d_in[0];
  const float* NZ = (const float*)d_in[1];
  const float* WG = (const float*)d_in[2];
  const float* NW = (const float*)d_in[3];
  float* OUT = (float*)d_out;
  char*  ws  = (char*)d_ws;
  ushort_t* WHI = (ushort_t*)(ws + WS_WHI);
  ushort_t* WLO = (ushort_t*)(ws + WS_WLO);
  double* ESUM = (double*)(ws + WS_SUM);
  int* FCNT  = (int*)(ws + WS_CNT);
  int* FLIST = (int*)(ws + WS_FLG);

  wsplit_kernel<<<dim3(64), dim3(256), 0, stream>>>(WG, WHI, WLO, ESUM, FCNT);
  moe_main<<<dim3(T_TOK/64), dim3(512), 0, stream>>>(X, NZ, WHI, WLO, NW, OUT, ESUM, FCNT, FLIST);
  moe_fixup<<<dim3(512), dim3(256), 0, stream>>>(X, NZ, WG, NW, OUT, FCNT, FLIST);
  moe_loss<<<dim3(1), dim3(64), 0, stream>>>(ESUM, OUT);
}

// Round 7
// 102.719 us; speedup vs baseline: 2.3416x; 1.0276x over previous
//
#include <hip/hip_runtime.h>
#include <hip/hip_bf16.h>

#define T_TOK 16384
#define D_DIM 2048
#define E_EXP 64
#define TAU   2e-3f

typedef __bf16 bf16x8 __attribute__((ext_vector_type(8)));
typedef float  f32x16 __attribute__((ext_vector_type(16)));
typedef unsigned short ushort_t;

// workspace layout (bytes)
#define WS_WHI  0                    // ushort[16384 granules][8] = 256KB, fragment-packed
#define WS_WLO  (256*1024)
#define WS_SUM  (512*1024)           // double[64] expert prob sums
#define WS_CNT  (512*1024 + 512)     // int flag count
#define WS_FLG  (512*1024 + 1024)    // int[T] flagged rows

__device__ __forceinline__ unsigned short bf16_rne(float x){
  unsigned int u = __float_as_uint(x);
  return (unsigned short)((u + 0x7FFFu + ((u >> 16) & 1u)) >> 16);
}

__device__ __forceinline__ void ins3(float& v1, int& i1, float& v2, int& i2,
                                     float& v3, int& i3, float v, int i){
  if (v > v1 || (v == v1 && i < i1)) { v3=v2; i3=i2; v2=v1; i2=i1; v1=v; i1=i; }
  else if (v > v2 || (v == v2 && i < i2)) { v3=v2; i3=i2; v2=v; i2=i; }
  else if (v > v3 || (v == v3 && i < i3)) { v3=v; i3=i; }
}

__device__ __forceinline__ void gload16(const void* g, const void* l){
  __builtin_amdgcn_global_load_lds(
      (const __attribute__((address_space(1))) unsigned int*)g,
      (__attribute__((address_space(3))) unsigned int*)l, 16, 0, 0);
}

// Fragment-pack W hi/lo bf16. Granule n = c*1024 + w*128 + e*64 + lane holds
// 8 elems: W[e*32 + (lane&31)][c*128 + w*16 + (lane>>5)*8 + j], j=0..7.
// Wave w's hi-fragments for all 16 chunks: 32 coalesced 1KB loads (prologue).
__global__ void wsplit_kernel(const float* __restrict__ W,
                              ushort_t* __restrict__ whi, ushort_t* __restrict__ wlo,
                              double* __restrict__ ESUM, int* __restrict__ FCNT){
  const int n = blockIdx.x * 256 + threadIdx.x;   // 64 blocks -> 16384 granules
  if (blockIdx.x == 0){
    if (threadIdx.x < 64) ESUM[threadIdx.x] = 0.0;
    else if (threadIdx.x == 64) *FCNT = 0;
  }
  const int lane = n & 63;
  const int e    = (n >> 6) & 1;
  const int w    = (n >> 7) & 7;
  const int c    = n >> 10;
  const float* src = W + (size_t)(e*32 + (lane & 31))*D_DIM
                       + c*128 + w*16 + (lane >> 5)*8;
  float4 w0 = *reinterpret_cast<const float4*>(src);
  float4 w1 = *reinterpret_cast<const float4*>(src + 4);
  float f[8] = {w0.x,w0.y,w0.z,w0.w,w1.x,w1.y,w1.z,w1.w};
  unsigned h[8], lo[8];
  #pragma unroll
  for (int i = 0; i < 8; ++i){
    h[i]  = bf16_rne(f[i]);
    lo[i] = bf16_rne(f[i] - __uint_as_float(h[i] << 16));
  }
  uint4 hv = { h[0]|(h[1]<<16),  h[2]|(h[3]<<16),  h[4]|(h[5]<<16),  h[6]|(h[7]<<16) };
  uint4 lv = { lo[0]|(lo[1]<<16), lo[2]|(lo[3]<<16), lo[4]|(lo[5]<<16), lo[6]|(lo[7]<<16) };
  *reinterpret_cast<uint4*>(whi + (size_t)n*8) = hv;
  *reinterpret_cast<uint4*>(wlo + (size_t)n*8) = lv;
}

// Main fused kernel. Tile 64 rows x 64 experts, BK=128, 16 fully-unrolled phases,
// grid 256 (1 block/CU), 8 waves = one k-step each. W-hi RESIDENT in VGPRs
// (loaded once, 128 VGPR); X(32KB)+W-lo(16KB) staged per chunk via global_load_lds
// into a 3-deep LDS pipeline (3x48KB); counted vmcnt keeps 2 chunks in flight.
__launch_bounds__(512, 1)
__global__ void moe_main(const float* __restrict__ X, const float* __restrict__ NZ,
                         const ushort_t* __restrict__ WHI, const ushort_t* __restrict__ WLO,
                         const float* __restrict__ NW, float* __restrict__ OUT,
                         double* __restrict__ ESUM, int* __restrict__ FCNT,
                         int* __restrict__ FLIST)
{
  __shared__ __align__(16) char smem[147456];   // 3 bufs x (32KB X | 16KB Wlo)

  const int tid  = threadIdx.x;
  const int lane = tid & 63;
  const int wv   = tid >> 6;        // 0..7 = k-step within each chunk
  const int r0   = blockIdx.x << 6;
  const int m    = lane & 31;
  const int kg   = lane >> 5;

  // --- X gload source pointers (pre-swizzled per-lane), q = 0..3 ---
  const char *pq0, *pq1, *pq2, *pq3;
  {
    const char* p[4];
    #pragma unroll
    for (int q = 0; q < 4; ++q){
      const int rw = wv*8 + q*2 + (lane >> 5);
      const int gp = lane & 31;
      const int g  = (gp & 24) | ((gp ^ rw) & 7);
      p[q] = (const char*)X + ((size_t)(r0 + rw)*D_DIM + g*4) * 4;
    }
    pq0 = p[0]; pq1 = p[1]; pq2 = p[2]; pq3 = p[3];
  }
  // --- W pointers (fragment-packed) ---
  const char* pwh = (const char*)WHI + wv*2048 + lane*16;
  const char* pwl = (const char*)WLO + wv*2048 + lane*16;

  // --- X fragment LDS byte offsets (chunk-invariant; rh1 = +16384 imm) ---
  const int g0  = wv*4 + kg*2;
  const int xo0 = m*512 + (((g0  ) & 24) | (((g0  ) ^ m) & 7))*16;
  const int xo1 = m*512 + (((g0+1) & 24) | (((g0+1) ^ m) & 7))*16;
  const int wloo = 32768 + wv*2048 + lane*16;

  f32x16 a00, a01, a10, a11;
  #pragma unroll
  for (int i = 0; i < 16; ++i){ a00[i]=0.f; a01[i]=0.f; a10[i]=0.f; a11[i]=0.f; }

  // --- prologue: resident W-hi (32 x 1KB coalesced loads -> 128 VGPR) ---
  uint4 wreg[32];
  #pragma unroll
  for (int c2 = 0; c2 < 32; ++c2)
    wreg[c2] = *reinterpret_cast<const uint4*>(pwh + (c2 >> 1)*16384 + (c2 & 1)*1024);

  #define ISSUE(C, BUF) do{                                                    \
    __builtin_amdgcn_sched_barrier(0);                                         \
    gload16(pq0 + (size_t)(C)*512, smem + (BUF) + wv*4096);                    \
    gload16(pq1 + (size_t)(C)*512, smem + (BUF) + wv*4096 + 1024);             \
    gload16(pq2 + (size_t)(C)*512, smem + (BUF) + wv*4096 + 2048);             \
    gload16(pq3 + (size_t)(C)*512, smem + (BUF) + wv*4096 + 3072);             \
    gload16(pwl + (size_t)(C)*16384,        smem + (BUF) + 32768 + wv*2048);         \
    gload16(pwl + (size_t)(C)*16384 + 1024, smem + (BUF) + 32768 + wv*2048 + 1024);  \
    __builtin_amdgcn_sched_barrier(0);                                         \
  }while(0)

  #define COMPUTE(C, BUF) do{                                                  \
    const char* Bx = smem + (BUF);                                             \
    float4 fa0 = *reinterpret_cast<const float4*>(Bx + xo0);                   \
    float4 fb0 = *reinterpret_cast<const float4*>(Bx + xo1);                   \
    float4 fa1 = *reinterpret_cast<const float4*>(Bx + 16384 + xo0);           \
    float4 fb1 = *reinterpret_cast<const float4*>(Bx + 16384 + xo1);           \
    bf16x8 bl0 = *reinterpret_cast<const bf16x8*>(Bx + wloo);                  \
    bf16x8 bl1 = *reinterpret_cast<const bf16x8*>(Bx + wloo + 1024);           \
    bf16x8 ah0, al0, ah1, al1;                                                 \
    { float fv[8] = {fa0.x,fa0.y,fa0.z,fa0.w,fb0.x,fb0.y,fb0.z,fb0.w};         \
      _Pragma("unroll")                                                        \
      for (int ii = 0; ii < 8; ++ii){                                          \
        __bf16 hh = (__bf16)fv[ii];                                            \
        ah0[ii] = hh; al0[ii] = (__bf16)(fv[ii] - (float)hh); } }              \
    { float fv[8] = {fa1.x,fa1.y,fa1.z,fa1.w,fb1.x,fb1.y,fb1.z,fb1.w};         \
      _Pragma("unroll")                                                        \
      for (int ii = 0; ii < 8; ++ii){                                          \
        __bf16 hh = (__bf16)fv[ii];                                            \
        ah1[ii] = hh; al1[ii] = (__bf16)(fv[ii] - (float)hh); } }              \
    bf16x8 bh0 = __builtin_bit_cast(bf16x8, wreg[(C)*2]);                      \
    bf16x8 bh1 = __builtin_bit_cast(bf16x8, wreg[(C)*2 + 1]);                  \
    a00 = __builtin_amdgcn_mfma_f32_32x32x16_bf16(ah0, bh0, a00, 0, 0, 0);     \
    a00 = __builtin_amdgcn_mfma_f32_32x32x16_bf16(al0, bh0, a00, 0, 0, 0);     \
    a00 = __builtin_amdgcn_mfma_f32_32x32x16_bf16(ah0, bl0, a00, 0, 0, 0);     \
    a01 = __builtin_amdgcn_mfma_f32_32x32x16_bf16(ah0, bh1, a01, 0, 0, 0);     \
    a01 = __builtin_amdgcn_mfma_f32_32x32x16_bf16(al0, bh1, a01, 0, 0, 0);     \
    a01 = __builtin_amdgcn_mfma_f32_32x32x16_bf16(ah0, bl1, a01, 0, 0, 0);     \
    a10 = __builtin_amdgcn_mfma_f32_32x32x16_bf16(ah1, bh0, a10, 0, 0, 0);     \
    a10 = __builtin_amdgcn_mfma_f32_32x32x16_bf16(al1, bh0, a10, 0, 0, 0);     \
    a10 = __builtin_amdgcn_mfma_f32_32x32x16_bf16(ah1, bl0, a10, 0, 0, 0);     \
    a11 = __builtin_amdgcn_mfma_f32_32x32x16_bf16(ah1, bh1, a11, 0, 0, 0);     \
    a11 = __builtin_amdgcn_mfma_f32_32x32x16_bf16(al1, bh1, a11, 0, 0, 0);     \
    a11 = __builtin_amdgcn_mfma_f32_32x32x16_bf16(ah1, bl1, a11, 0, 0, 0);     \
  }while(0)

  #define WAITV(N) do{ asm volatile("s_waitcnt vmcnt(" #N ")" ::: "memory");   \
                       __builtin_amdgcn_sched_barrier(0); }while(0)

  #define PHASE(C, TOK, DOISS) do{                                             \
    WAITV(TOK); __builtin_amdgcn_s_barrier();                                  \
    COMPUTE(C, ((C) % 3) * 49152);                                             \
    __builtin_amdgcn_s_barrier();                                              \
    if (DOISS) ISSUE((C) + 3, ((C) % 3) * 49152);                              \
  }while(0)

  ISSUE(0, 0); ISSUE(1, 49152); ISSUE(2, 98304);
  WAITV(18);   // resident W-hi complete; 3 staged chunks still in flight

  PHASE(0,  12, 1);  PHASE(1,  12, 1);  PHASE(2,  12, 1);  PHASE(3,  12, 1);
  PHASE(4,  12, 1);  PHASE(5,  12, 1);  PHASE(6,  12, 1);  PHASE(7,  12, 1);
  PHASE(8,  12, 1);  PHASE(9,  12, 1);  PHASE(10, 12, 1);  PHASE(11, 12, 1);
  PHASE(12, 12, 1);  PHASE(13, 12, 0);  PHASE(14, 6,  0);  PHASE(15, 0,  0);

  #undef PHASE
  #undef WAITV
  #undef COMPUTE
  #undef ISSUE

  // ---- epilogue: 8-way k reduction tree (8 -> 4 -> 1) ----
  // red[b] = smem + {0, 16K, 32K, 49152}
  float* redp = (float*)(smem + ((wv & 3) < 3 ? (wv & 3)*16384 : 49152));
  __syncthreads();
  if (wv < 4){
    #pragma unroll
    for (int r = 0; r < 16; ++r){
      int rr = (r & 3) + ((r >> 2) << 3) + (kg << 2);   // verified 32x32 C/D layout
      redp[rr*64 + m]            = a00[r];
      redp[rr*64 + 32 + m]       = a01[r];
      redp[(32 + rr)*64 + m]     = a10[r];
      redp[(32 + rr)*64 + 32 + m]= a11[r];
    }
  }
  __syncthreads();
  if (wv >= 4){
    #pragma unroll
    for (int r = 0; r < 16; ++r){
      int rr = (r & 3) + ((r >> 2) << 3) + (kg << 2);
      redp[rr*64 + m]             += a00[r];
      redp[rr*64 + 32 + m]        += a01[r];
      redp[(32 + rr)*64 + m]      += a10[r];
      redp[(32 + rr)*64 + 32 + m] += a11[r];
    }
  }
  __syncthreads();
  float* lgts = (float*)(smem);            // [64][64]
  {
    const float4* r1 = (const float4*)(smem + 16384);
    const float4* r2 = (const float4*)(smem + 32768);
    const float4* r3 = (const float4*)(smem + 49152);
    float4* r0 = (float4*)(smem);
    #pragma unroll
    for (int i = 0; i < 2; ++i){
      int idx = tid*2 + i;
      float4 s = r0[idx];
      float4 b = r1[idx], c = r2[idx], d = r3[idx];
      s.x += b.x + c.x + d.x; s.y += b.y + c.y + d.y;
      s.z += b.z + c.z + d.z; s.w += b.w + c.w + d.w;
      r0[idx] = s;
    }
  }
  __syncthreads();

  float* nzs = (float*)(smem + 16384);     // [64][64]
  float* prb = (float*)(smem + 32768);     // [64][64]
  float* nws = (float*)(smem + 65536);     // [64]
  {
    const int rw = tid >> 3, cb = (tid & 7) * 8;
    *reinterpret_cast<float4*>(&nzs[rw*64 + cb]) =
      *reinterpret_cast<const float4*>(NZ + (size_t)(r0 + rw)*E_EXP + cb);
    *reinterpret_cast<float4*>(&nzs[rw*64 + cb + 4]) =
      *reinterpret_cast<const float4*>(NZ + (size_t)(r0 + rw)*E_EXP + cb + 4);
  }
  if (tid < 64) nws[tid] = NW[tid];
  __syncthreads();

  // gating: 8 waves x 8 rows, 8 lanes per row, 8 experts per lane
  {
    const int rrow = (wv << 3) + (lane >> 3);
    const int j    = lane & 7;
    const int trow = r0 + rrow;
    float cl[8];
    float v1 = -INFINITY, v2 = -INFINITY, v3 = -INFINITY;
    int   i1 = 1 << 29,   i2 = 1 << 29,   i3 = 1 << 29;
    #pragma unroll
    for (int mm = 0; mm < 8; ++mm){
      int q = j + (mm << 3);
      float lg = lgts[rrow*64 + q];
      cl[mm] = lg;
      float vn = fmaf(nzs[rrow*64 + q], nws[q], lg);   // NOISY_STD = 1
      ins3(v1,i1,v2,i2,v3,i3, vn, q);
    }
    #pragma unroll
    for (int d = 1; d < 8; d <<= 1){
      float ov1 = __shfl_xor(v1, d, 8), ov2 = __shfl_xor(v2, d, 8), ov3 = __shfl_xor(v3, d, 8);
      int   oi1 = __shfl_xor(i1, d, 8), oi2 = __shfl_xor(i2, d, 8), oi3 = __shfl_xor(i3, d, 8);
      ins3(v1,i1,v2,i2,v3,i3, ov1, oi1);
      ins3(v1,i1,v2,i2,v3,i3, ov2, oi2);
      ins3(v1,i1,v2,i2,v3,i3, ov3, oi3);
    }
    float e1 = expf(v2 - v1);
    float g0g = 1.0f / (1.0f + e1);
    float g1g = e1 * g0g;

    float mx = cl[0];
    #pragma unroll
    for (int mm = 1; mm < 8; ++mm) mx = fmaxf(mx, cl[mm]);
    #pragma unroll
    for (int d = 1; d < 8; d <<= 1) mx = fmaxf(mx, __shfl_xor(mx, d, 8));
    float sum = 0.0f, exv[8];
    #pragma unroll
    for (int mm = 0; mm < 8; ++mm){ exv[mm] = expf(cl[mm] - mx); sum += exv[mm]; }
    #pragma unroll
    for (int d = 1; d < 8; d <<= 1) sum += __shfl_xor(sum, d, 8);
    float inv = 1.0f / sum;
    #pragma unroll
    for (int mm = 0; mm < 8; ++mm) prb[rrow*64 + j + (mm << 3)] = exv[mm] * inv;

    if (j == 0){
      OUT[(size_t)T_TOK*E_EXP + (size_t)trow*2]     = (float)i1;
      OUT[(size_t)T_TOK*E_EXP + (size_t)trow*2 + 1] = (float)i2;
      if ((v1 - v2 < TAU) || (v2 - v3 < TAU)){   // near-tie -> fp64 fixup
        int slot = atomicAdd(FCNT, 1);
        FLIST[slot] = trow;
      }
    }
    #pragma unroll
    for (int mm = 0; mm < 8; ++mm){
      int q = j + (mm << 3);
      lgts[rrow*64 + q] = (q == i1) ? g0g : ((q == i2) ? g1g : 0.0f);
    }
  }
  __syncthreads();

  // coalesced gates write
  {
    const int rw = tid >> 3, cb = (tid & 7) * 8;
    *reinterpret_cast<float4*>(OUT + (size_t)(r0 + rw)*E_EXP + cb) =
      *reinterpret_cast<const float4*>(&lgts[rw*64 + cb]);
    *reinterpret_cast<float4*>(OUT + (size_t)(r0 + rw)*E_EXP + cb + 4) =
      *reinterpret_cast<const float4*>(&lgts[rw*64 + cb + 4]);
  }
  // per-expert prob column sums -> one f64 atomic per expert per block
  if (tid < 64){
    float s0 = 0.0f;
    #pragma unroll 8
    for (int rr2 = 0; rr2 < 64; ++rr2) s0 += prb[rr2*64 + tid];
    atomicAdd(&ESUM[tid], (double)s0);
  }
}

// fp64-exact recompute of flagged (near-tie) rows; coalesced, one block/row.
__launch_bounds__(256)
__global__ void moe_fixup(const float* __restrict__ X, const float* __restrict__ NZ,
                          const float* __restrict__ WG, const float* __restrict__ NW,
                          float* __restrict__ OUT, const int* __restrict__ FCNT,
                          const int* __restrict__ FLIST)
{
  __shared__ __align__(16) float xl[2048];
  __shared__ double lz[64];
  __shared__ int   si1, si2;
  __shared__ float sg0, sg1;
  const int n    = *FCNT;
  const int lane = threadIdx.x & 63;
  const int wv   = threadIdx.x >> 6;
  for (int idx = blockIdx.x; idx < n; idx += gridDim.x){
    const int t = FLIST[idx];
    {
      int off = threadIdx.x * 8;
      *reinterpret_cast<float4*>(xl + off) =
        *reinterpret_cast<const float4*>(X + (size_t)t*D_DIM + off);
      *reinterpret_cast<float4*>(xl + off + 4) =
        *reinterpret_cast<const float4*>(X + (size_t)t*D_DIM + off + 4);
    }
    __syncthreads();
    for (int s = 0; s < 16; ++s){
      const int e = wv*16 + s;
      const float* wr = WG + (size_t)e*D_DIM;
      double acc = 0.0;
      #pragma unroll
      for (int it = 0; it < 8; ++it){
        float4 w4 = *reinterpret_cast<const float4*>(wr + it*256 + lane*4);
        float4 x4 = *reinterpret_cast<const float4*>(xl + it*256 + lane*4);
        acc += (double)x4.x * (double)w4.x;
        acc += (double)x4.y * (double)w4.y;
        acc += (double)x4.z * (double)w4.z;
        acc += (double)x4.w * (double)w4.w;
      }
      #pragma unroll
      for (int off = 1; off < 64; off <<= 1) acc += __shfl_xor(acc, off, 64);
      if (lane == 0)
        lz[e] = acc + (double)NZ[(size_t)t*E_EXP + e] * (double)NW[e];
    }
    __syncthreads();
    if (threadIdx.x == 0){
      double b1 = -1e300, b2 = -1e300; int j1 = 0, j2 = 0;
      for (int q = 0; q < 64; ++q){
        double v = lz[q];
        if (v > b1){ b2 = b1; j2 = j1; b1 = v; j1 = q; }
        else if (v > b2){ b2 = v; j2 = q; }
      }
      double ee = exp(b2 - b1);
      sg0 = (float)(1.0 / (1.0 + ee));
      sg1 = (float)(ee / (1.0 + ee));
      si1 = j1; si2 = j2;
      OUT[(size_t)T_TOK*E_EXP + (size_t)t*2]     = (float)j1;
      OUT[(size_t)T_TOK*E_EXP + (size_t)t*2 + 1] = (float)j2;
    }
    __syncthreads();
    if (threadIdx.x < 64)
      OUT[(size_t)t*E_EXP + threadIdx.x] = (threadIdx.x == si1) ? sg0 :
                                           ((threadIdx.x == si2) ? sg1 : 0.0f);
    __syncthreads();
  }
}

__global__ void moe_loss(const double* __restrict__ ESUM, float* __restrict__ OUT){
  const int e = threadIdx.x;   // 64 threads
  double d = ESUM[e] * (1.0 / T_TOK) - (1.0 / 64.0);
  double sq = d * d;
  #pragma unroll
  for (int off = 1; off < 64; off <<= 1) sq += __shfl_xor(sq, off, 64);
  if (e == 0) OUT[(size_t)T_TOK*E_EXP + T_TOK*2] = (float)(sq * (0.01 / 64.0));
}

extern "C" void kernel_launch(void* const* d_in, const int* in_sizes, int n_in,
                              void* d_out, int out_size, void* d_ws, size_t ws_size,
                              hipStream_t stream)
{
  const float* X  = (const float*)d_in[0];
  const float* NZ = (const float*)d_in[1];
  const float* WG = (const float*)d_in[2];
  const float* NW = (const float*)d_in[3];
  float* OUT = (float*)d_out;
  char*  ws  = (char*)d_ws;
  ushort_t* WHI = (ushort_t*)(ws + WS_WHI);
  ushort_t* WLO = (ushort_t*)(ws + WS_WLO);
  double* ESUM = (double*)(ws + WS_SUM);
  int* FCNT  = (int*)(ws + WS_CNT);
  int* FLIST = (int*)(ws + WS_FLG);

  wsplit_kernel<<<dim3(64), dim3(256), 0, stream>>>(WG, WHI, WLO, ESUM, FCNT);
  moe_main<<<dim3(T_TOK/64), dim3(512), 0, stream>>>(X, NZ, WHI, WLO, NW, OUT, ESUM, FCNT, FLIST);
  moe_fixup<<<dim3(512), dim3(256), 0, stream>>>(X, NZ, WG, NW, OUT, FCNT, FLIST);
  moe_loss<<<dim3(1), dim3(64), 0, stream>>>(ESUM, OUT);
}

// Round 8
// 102.328 us; speedup vs baseline: 2.3505x; 1.0038x over previous
//
#include <hip/hip_runtime.h>
#include <hip/hip_bf16.h>

#define T_TOK 16384
#define D_DIM 2048
#define E_EXP 64
#define TAU   2e-3f

typedef __bf16 bf16x8 __attribute__((ext_vector_type(8)));
typedef float  f32x4  __attribute__((ext_vector_type(4)));
typedef unsigned short ushort_t;

// workspace layout (bytes)
#define WS_WHI  0                    // ushort[16384 granules][8] = 256KB, fragment-packed
#define WS_WLO  (256*1024)
#define WS_SUM  (512*1024)           // double[64] expert prob sums
#define WS_CNT  (512*1024 + 512)     // int flag count
#define WS_FLG  (512*1024 + 1024)    // int[T] flagged rows

__device__ __forceinline__ unsigned short bf16_rne(float x){
  unsigned int u = __float_as_uint(x);
  return (unsigned short)((u + 0x7FFFu + ((u >> 16) & 1u)) >> 16);
}

__device__ __forceinline__ void ins3(float& v1, int& i1, float& v2, int& i2,
                                     float& v3, int& i3, float v, int i){
  if (v > v1 || (v == v1 && i < i1)) { v3=v2; i3=i2; v2=v1; i2=i1; v1=v; i1=i; }
  else if (v > v2 || (v == v2 && i < i2)) { v3=v2; i3=i2; v2=v; i2=i; }
  else if (v > v3 || (v == v3 && i < i3)) { v3=v; i3=i; }
}

__device__ __forceinline__ void gload16(const void* g, const void* l){
  __builtin_amdgcn_global_load_lds(
      (const __attribute__((address_space(1))) unsigned int*)g,
      (__attribute__((address_space(3))) unsigned int*)l, 16, 0, 0);
}

// Fragment-pack W hi/lo bf16 for 16x16x32 B-fragments.
// Granule G = ((kh*16 + c)*8 + s*4 + t)*64 + (kg*16 + (e&15)) holds
// W[e = t*16 + (e&15)][kh*1024 + c*64 + s*32 + kg*8 + j], j = 0..7.
// Reader (wave kh) loads 1KB contiguous per (c, s*4+t) -> perfectly coalesced.
__global__ void wsplit_kernel(const float* __restrict__ W,
                              ushort_t* __restrict__ whi, ushort_t* __restrict__ wlo,
                              double* __restrict__ ESUM, int* __restrict__ FCNT){
  const int n = blockIdx.x * 256 + threadIdx.x;   // 64 blocks -> 16384 granules
  if (blockIdx.x == 0){
    if (threadIdx.x < 64) ESUM[threadIdx.x] = 0.0;
    else if (threadIdx.x == 64) *FCNT = 0;
  }
  const int e  = n >> 8;          // coalesced read side
  const int k0 = (n & 255) * 8;
  const float* src = W + (size_t)e*D_DIM + k0;
  float4 w0 = *reinterpret_cast<const float4*>(src);
  float4 w1 = *reinterpret_cast<const float4*>(src + 4);
  float f[8] = {w0.x,w0.y,w0.z,w0.w,w1.x,w1.y,w1.z,w1.w};
  unsigned h[8], lo[8];
  #pragma unroll
  for (int i = 0; i < 8; ++i){
    h[i]  = bf16_rne(f[i]);
    lo[i] = bf16_rne(f[i] - __uint_as_float(h[i] << 16));
  }
  uint4 hv = { h[0]|(h[1]<<16),  h[2]|(h[3]<<16),  h[4]|(h[5]<<16),  h[6]|(h[7]<<16) };
  uint4 lv = { lo[0]|(lo[1]<<16), lo[2]|(lo[3]<<16), lo[4]|(lo[5]<<16), lo[6]|(lo[7]<<16) };
  const int kh = k0 >> 10, c = (k0 >> 6) & 15, s = (k0 >> 5) & 1, kg = (k0 >> 3) & 3;
  const int t  = e >> 4;
  const int G  = ((kh*16 + c)*8 + s*4 + t)*64 + kg*16 + (e & 15);
  *reinterpret_cast<uint4*>(whi + (size_t)G*8) = hv;
  *reinterpret_cast<uint4*>(wlo + (size_t)G*8) = lv;
}

// Main fused kernel — BARRIER-FREE mainloop. Grid 256 x 512thr (8 waves/block,
// 2/SIMD). Wave = (pair = wv>>1 -> rows pair*16, kh = wv&1 -> K-half).
// Per wave: 16 rows x 64 experts x 1024 k, 16 chunks of 64 k. X staged into a
// WAVE-PRIVATE LDS slice via global_load_lds (per-wave counted vmcnt(20), no
// barriers); W global->VGPR from packed layout (compiler-tracked). 16x16x32 MFMA,
// 3-term split-bf16. Epilogue: one K-half reduction + gating (3 barriers total).
__launch_bounds__(512, 2)
__global__ void moe_main(const float* __restrict__ X, const float* __restrict__ NZ,
                         const ushort_t* __restrict__ WHI, const ushort_t* __restrict__ WLO,
                         const float* __restrict__ NW, float* __restrict__ OUT,
                         double* __restrict__ ESUM, int* __restrict__ FCNT,
                         int* __restrict__ FLIST)
{
  __shared__ __align__(16) char smem[65536];   // 8 waves x 2 bufs x 4KB (mainloop)

  const int tid  = threadIdx.x;
  const int lane = tid & 63;
  const int wv   = tid >> 6;        // 0..7
  const int kh   = wv & 1;          // K half
  const int pair = wv >> 1;         // row group
  const int r0   = blockIdx.x << 6;
  const int pr0  = r0 + pair*16;

  char* ldsbase = smem + wv*8192;   // wave-private 2 x 4KB

  // --- X gload source pointers (pre-swizzled per-lane), q = 0..3 ---
  // dst granule n = q*64 + lane -> row = q*4 + (lane>>4), phys g = lane&15;
  // logical g = phys ^ row (involution, applied again at read time).
  const char *px0, *px1, *px2, *px3;
  {
    const char* p[4];
    #pragma unroll
    for (int q = 0; q < 4; ++q){
      const int row = q*4 + (lane >> 4);
      const int g   = (lane & 15) ^ row;
      p[q] = (const char*)X + ((size_t)(pr0 + row)*D_DIM + kh*1024 + g*4) * 4;
    }
    px0 = p[0]; px1 = p[1]; px2 = p[2]; px3 = p[3];
  }
  // --- W fragment pointers ---
  const char* pwh = (const char*)WHI + (size_t)kh*131072 + lane*16;
  const char* pwl = (const char*)WLO + (size_t)kh*131072 + lane*16;

  // --- X fragment LDS byte offsets (chunk-invariant) ---
  const int arow = lane & 15, akg = lane >> 4;
  const int xo00 = arow*256 + (((0*8 + akg*2 + 0) ^ arow) << 4);
  const int xo01 = arow*256 + (((0*8 + akg*2 + 1) ^ arow) << 4);
  const int xo10 = arow*256 + (((1*8 + akg*2 + 0) ^ arow) << 4);
  const int xo11 = arow*256 + (((1*8 + akg*2 + 1) ^ arow) << 4);

  f32x4 acc[4];
  #pragma unroll
  for (int t = 0; t < 4; ++t){ acc[t][0]=0.f; acc[t][1]=0.f; acc[t][2]=0.f; acc[t][3]=0.f; }

  uint4 wAh[8], wAl[8], wBh[8], wBl[8];

  #define LOADX(C, BUF) do{                                                    \
    __builtin_amdgcn_sched_barrier(0);                                         \
    gload16(px0 + (size_t)(C)*256, ldsbase + (BUF)*4096);                      \
    gload16(px1 + (size_t)(C)*256, ldsbase + (BUF)*4096 + 1024);               \
    gload16(px2 + (size_t)(C)*256, ldsbase + (BUF)*4096 + 2048);               \
    gload16(px3 + (size_t)(C)*256, ldsbase + (BUF)*4096 + 3072);               \
    __builtin_amdgcn_sched_barrier(0);                                         \
  }while(0)

  #define LOADW(C, WH, WL) do{                                                 \
    _Pragma("unroll")                                                          \
    for (int i = 0; i < 8; ++i){                                               \
      WH[i] = *reinterpret_cast<const uint4*>(pwh + (size_t)(C)*8192 + i*1024);\
      WL[i] = *reinterpret_cast<const uint4*>(pwl + (size_t)(C)*8192 + i*1024);\
    }                                                                          \
  }while(0)

  #define CVT8(fa, fb, ah, al) do{                                             \
    float fv[8] = {fa.x,fa.y,fa.z,fa.w,fb.x,fb.y,fb.z,fb.w};                   \
    _Pragma("unroll")                                                          \
    for (int ii = 0; ii < 8; ++ii){                                            \
      __bf16 hh = (__bf16)fv[ii];                                              \
      ah[ii] = hh; al[ii] = (__bf16)(fv[ii] - (float)hh);                      \
    }                                                                          \
  }while(0)

  #define COMPUTE(BUF, WH, WL) do{                                             \
    const char* Bx = ldsbase + (BUF)*4096;                                     \
    { float4 fa = *reinterpret_cast<const float4*>(Bx + xo00);                 \
      float4 fb = *reinterpret_cast<const float4*>(Bx + xo01);                 \
      bf16x8 ah, al; CVT8(fa, fb, ah, al);                                     \
      _Pragma("unroll")                                                        \
      for (int t = 0; t < 4; ++t){                                             \
        bf16x8 bh = __builtin_bit_cast(bf16x8, WH[t]);                         \
        bf16x8 bl = __builtin_bit_cast(bf16x8, WL[t]);                         \
        acc[t] = __builtin_amdgcn_mfma_f32_16x16x32_bf16(ah, bh, acc[t],0,0,0);\
        acc[t] = __builtin_amdgcn_mfma_f32_16x16x32_bf16(al, bh, acc[t],0,0,0);\
        acc[t] = __builtin_amdgcn_mfma_f32_16x16x32_bf16(ah, bl, acc[t],0,0,0);\
      } }                                                                      \
    { float4 fa = *reinterpret_cast<const float4*>(Bx + xo10);                 \
      float4 fb = *reinterpret_cast<const float4*>(Bx + xo11);                 \
      bf16x8 ah, al; CVT8(fa, fb, ah, al);                                     \
      _Pragma("unroll")                                                        \
      for (int t = 0; t < 4; ++t){                                             \
        bf16x8 bh = __builtin_bit_cast(bf16x8, WH[4+t]);                       \
        bf16x8 bl = __builtin_bit_cast(bf16x8, WL[4+t]);                       \
        acc[t] = __builtin_amdgcn_mfma_f32_16x16x32_bf16(ah, bh, acc[t],0,0,0);\
        acc[t] = __builtin_amdgcn_mfma_f32_16x16x32_bf16(al, bh, acc[t],0,0,0);\
        acc[t] = __builtin_amdgcn_mfma_f32_16x16x32_bf16(ah, bl, acc[t],0,0,0);\
      } }                                                                      \
  }while(0)

  #define WAITX(N) do{ asm volatile("s_waitcnt vmcnt(" #N ")" ::: "memory");   \
                       __builtin_amdgcn_sched_barrier(0); }while(0)

  // prologue: chunks 0 (buf0/setA) and 1 (buf1/setB)
  LOADX(0, 0); LOADW(0, wAh, wAl);
  LOADX(1, 1); LOADW(1, wBh, wBl);

  #pragma unroll 1
  for (int g = 0; g < 7; ++g){
    const int c = 2*g;
    WAITX(20);
    COMPUTE(0, wAh, wAl);
    LOADX(c+2, 0); LOADW(c+2, wAh, wAl);
    WAITX(20);
    COMPUTE(1, wBh, wBl);
    LOADX(c+3, 1); LOADW(c+3, wBh, wBl);
  }
  WAITX(20); COMPUTE(0, wAh, wAl);
  WAITX(0);  COMPUTE(1, wBh, wBl);

  #undef WAITX
  #undef COMPUTE
  #undef CVT8
  #undef LOADW
  #undef LOADX

  // ---- epilogue: K-half reduction (deterministic 2-phase), then gating ----
  float* lgts = (float*)(smem);            // [64][64] = 16KB
  float* nzs  = (float*)(smem + 16384);    // [64][64]
  float* prb  = (float*)(smem + 32768);    // [64][64]
  float* nws  = (float*)(smem + 49152);    // [64]

  __syncthreads();
  // C/D layout 16x16 (verified m89): col = lane&15, row = (lane>>4)*4 + reg
  if (kh == 0){
    #pragma unroll
    for (int t = 0; t < 4; ++t)
      #pragma unroll
      for (int r = 0; r < 4; ++r)
        lgts[(pair*16 + akg*4 + r)*64 + t*16 + arow] = acc[t][r];
  }
  __syncthreads();
  if (kh == 1){
    #pragma unroll
    for (int t = 0; t < 4; ++t)
      #pragma unroll
      for (int r = 0; r < 4; ++r)
        lgts[(pair*16 + akg*4 + r)*64 + t*16 + arow] += acc[t][r];
  }
  // stage noise + noise_weight (512 threads x 8 floats)
  {
    const int rw = tid >> 3, cb = (tid & 7) * 8;
    *reinterpret_cast<float4*>(&nzs[rw*64 + cb]) =
      *reinterpret_cast<const float4*>(NZ + (size_t)(r0 + rw)*E_EXP + cb);
    *reinterpret_cast<float4*>(&nzs[rw*64 + cb + 4]) =
      *reinterpret_cast<const float4*>(NZ + (size_t)(r0 + rw)*E_EXP + cb + 4);
  }
  if (tid < 64) nws[tid] = NW[tid];
  __syncthreads();

  // gating: 8 waves x 8 rows, 8 lanes per row, 8 experts per lane
  {
    const int rrow = (wv << 3) + (lane >> 3);
    const int j    = lane & 7;
    const int trow = r0 + rrow;
    float cl[8];
    float v1 = -INFINITY, v2 = -INFINITY, v3 = -INFINITY;
    int   i1 = 1 << 29,   i2 = 1 << 29,   i3 = 1 << 29;
    #pragma unroll
    for (int mm = 0; mm < 8; ++mm){
      int q = j + (mm << 3);
      float lg = lgts[rrow*64 + q];
      cl[mm] = lg;
      float vn = fmaf(nzs[rrow*64 + q], nws[q], lg);   // NOISY_STD = 1
      ins3(v1,i1,v2,i2,v3,i3, vn, q);
    }
    #pragma unroll
    for (int d = 1; d < 8; d <<= 1){
      float ov1 = __shfl_xor(v1, d, 8), ov2 = __shfl_xor(v2, d, 8), ov3 = __shfl_xor(v3, d, 8);
      int   oi1 = __shfl_xor(i1, d, 8), oi2 = __shfl_xor(i2, d, 8), oi3 = __shfl_xor(i3, d, 8);
      ins3(v1,i1,v2,i2,v3,i3, ov1, oi1);
      ins3(v1,i1,v2,i2,v3,i3, ov2, oi2);
      ins3(v1,i1,v2,i2,v3,i3, ov3, oi3);
    }
    float e1 = expf(v2 - v1);
    float g0g = 1.0f / (1.0f + e1);
    float g1g = e1 * g0g;

    float mx = cl[0];
    #pragma unroll
    for (int mm = 1; mm < 8; ++mm) mx = fmaxf(mx, cl[mm]);
    #pragma unroll
    for (int d = 1; d < 8; d <<= 1) mx = fmaxf(mx, __shfl_xor(mx, d, 8));
    float sum = 0.0f, exv[8];
    #pragma unroll
    for (int mm = 0; mm < 8; ++mm){ exv[mm] = expf(cl[mm] - mx); sum += exv[mm]; }
    #pragma unroll
    for (int d = 1; d < 8; d <<= 1) sum += __shfl_xor(sum, d, 8);
    float inv = 1.0f / sum;
    #pragma unroll
    for (int mm = 0; mm < 8; ++mm) prb[rrow*64 + j + (mm << 3)] = exv[mm] * inv;

    if (j == 0){
      OUT[(size_t)T_TOK*E_EXP + (size_t)trow*2]     = (float)i1;
      OUT[(size_t)T_TOK*E_EXP + (size_t)trow*2 + 1] = (float)i2;
      if ((v1 - v2 < TAU) || (v2 - v3 < TAU)){   // near-tie -> fp64 fixup
        int slot = atomicAdd(FCNT, 1);
        FLIST[slot] = trow;
      }
    }
    #pragma unroll
    for (int mm = 0; mm < 8; ++mm){
      int q = j + (mm << 3);
      lgts[rrow*64 + q] = (q == i1) ? g0g : ((q == i2) ? g1g : 0.0f);
    }
  }
  __syncthreads();

  // coalesced gates write
  {
    const int rw = tid >> 3, cb = (tid & 7) * 8;
    *reinterpret_cast<float4*>(OUT + (size_t)(r0 + rw)*E_EXP + cb) =
      *reinterpret_cast<const float4*>(&lgts[rw*64 + cb]);
    *reinterpret_cast<float4*>(OUT + (size_t)(r0 + rw)*E_EXP + cb + 4) =
      *reinterpret_cast<const float4*>(&lgts[rw*64 + cb + 4]);
  }
  // per-expert prob column sums -> one f64 atomic per expert per block
  if (tid < 64){
    float s0 = 0.0f;
    #pragma unroll 8
    for (int rr2 = 0; rr2 < 64; ++rr2) s0 += prb[rr2*64 + tid];
    atomicAdd(&ESUM[tid], (double)s0);
  }
}

// fp64-exact recompute of flagged (near-tie) rows; coalesced, one block/row.
__launch_bounds__(256)
__global__ void moe_fixup(const float* __restrict__ X, const float* __restrict__ NZ,
                          const float* __restrict__ WG, const float* __restrict__ NW,
                          float* __restrict__ OUT, const int* __restrict__ FCNT,
                          const int* __restrict__ FLIST)
{
  __shared__ __align__(16) float xl[2048];
  __shared__ double lz[64];
  __shared__ int   si1, si2;
  __shared__ float sg0, sg1;
  const int n    = *FCNT;
  const int lane = threadIdx.x & 63;
  const int wv   = threadIdx.x >> 6;
  for (int idx = blockIdx.x; idx < n; idx += gridDim.x){
    const int t = FLIST[idx];
    {
      int off = threadIdx.x * 8;
      *reinterpret_cast<float4*>(xl + off) =
        *reinterpret_cast<const float4*>(X + (size_t)t*D_DIM + off);
      *reinterpret_cast<float4*>(xl + off + 4) =
        *reinterpret_cast<const float4*>(X + (size_t)t*D_DIM + off + 4);
    }
    __syncthreads();
    for (int s = 0; s < 16; ++s){
      const int e = wv*16 + s;
      const float* wr = WG + (size_t)e*D_DIM;
      double acc = 0.0;
      #pragma unroll
      for (int it = 0; it < 8; ++it){
        float4 w4 = *reinterpret_cast<const float4*>(wr + it*256 + lane*4);
        float4 x4 = *reinterpret_cast<const float4*>(xl + it*256 + lane*4);
        acc += (double)x4.x * (double)w4.x;
        acc += (double)x4.y * (double)w4.y;
        acc += (double)x4.z * (double)w4.z;
        acc += (double)x4.w * (double)w4.w;
      }
      #pragma unroll
      for (int off = 1; off < 64; off <<= 1) acc += __shfl_xor(acc, off, 64);
      if (lane == 0)
        lz[e] = acc + (double)NZ[(size_t)t*E_EXP + e] * (double)NW[e];
    }
    __syncthreads();
    if (threadIdx.x == 0){
      double b1 = -1e300, b2 = -1e300; int j1 = 0, j2 = 0;
      for (int q = 0; q < 64; ++q){
        double v = lz[q];
        if (v > b1){ b2 = b1; j2 = j1; b1 = v; j1 = q; }
        else if (v > b2){ b2 = v; j2 = q; }
      }
      double ee = exp(b2 - b1);
      sg0 = (float)(1.0 / (1.0 + ee));
      sg1 = (float)(ee / (1.0 + ee));
      si1 = j1; si2 = j2;
      OUT[(size_t)T_TOK*E_EXP + (size_t)t*2]     = (float)j1;
      OUT[(size_t)T_TOK*E_EXP + (size_t)t*2 + 1] = (float)j2;
    }
    __syncthreads();
    if (threadIdx.x < 64)
      OUT[(size_t)t*E_EXP + threadIdx.x] = (threadIdx.x == si1) ? sg0 :
                                           ((threadIdx.x == si2) ? sg1 : 0.0f);
    __syncthreads();
  }
}

__global__ void moe_loss(const double* __restrict__ ESUM, float* __restrict__ OUT){
  const int e = threadIdx.x;   // 64 threads
  double d = ESUM[e] * (1.0 / T_TOK) - (1.0 / 64.0);
  double sq = d * d;
  #pragma unroll
  for (int off = 1; off < 64; off <<= 1) sq += __shfl_xor(sq, off, 64);
  if (e == 0) OUT[(size_t)T_TOK*E_EXP + T_TOK*2] = (float)(sq * (0.01 / 64.0));
}

extern "C" void kernel_launch(void* const* d_in, const int* in_sizes, int n_in,
                              void* d_out, int out_size, void* d_ws, size_t ws_size,
                              hipStream_t stream)
{
  const float* X  = (const float*)d_in[0];
  const float* NZ = (const float*)d_in[1];
  const float* WG = (const float*)d_in[2];
  const float* NW = (const float*)d_in[3];
  float* OUT = (float*)d_out;
  char*  ws  = (char*)d_ws;
  ushort_t* WHI = (ushort_t*)(ws + WS_WHI);
  ushort_t* WLO = (ushort_t*)(ws + WS_WLO);
  double* ESUM = (double*)(ws + WS_SUM);
  int* FCNT  = (int*)(ws + WS_CNT);
  int* FLIST = (int*)(ws + WS_FLG);

  wsplit_kernel<<<dim3(64), dim3(256), 0, stream>>>(WG, WHI, WLO, ESUM, FCNT);
  moe_main<<<dim3(T_TOK/64), dim3(512), 0, stream>>>(X, NZ, WHI, WLO, NW, OUT, ESUM, FCNT, FLIST);
  moe_fixup<<<dim3(512), dim3(256), 0, stream>>>(X, NZ, WG, NW, OUT, FCNT, FLIST);
  moe_loss<<<dim3(1), dim3(64), 0, stream>>>(ESUM, OUT);
}